// Round 5
// baseline (588.596 us; speedup 1.0000x reference)
//
#include <hip/hip_runtime.h>
#include <hip/hip_bf16.h>
#include <hip/hip_fp16.h>

#define N_NODES 50000
#define N_EDGES 1600000
#define HEADS 8
#define HD 32
#define FIN 256
#define HID 256

typedef unsigned short u16;
typedef unsigned int u32;

typedef short s8v __attribute__((ext_vector_type(8)));   // 8 bf16 (4 VGPRs)
typedef float f4v __attribute__((ext_vector_type(4)));   // 4 fp32 acc
typedef float fx4 __attribute__((ext_vector_type(4)));   // clang vec (NT-able)

// pack 2 fp32 -> 2 bf16 (RNE) in one u32; lowers to v_cvt_pk_bf16_f32 on gfx950
__device__ __forceinline__ u32 pk2(float lo, float hi) {
  __hip_bfloat162 b = __float22bfloat162_rn(make_float2(lo, hi));
  union { __hip_bfloat162 b2; u32 u; } c;
  c.b2 = b;
  return c.u;
}

// ---------------- one-time W pre-pack: Wp[col*256+k] = bf16(W[h][k][d]) -----
__global__ __launch_bounds__(256) void k_prepw(const float* __restrict__ W,
                                               u16* __restrict__ Wp) {
  int id = blockIdx.x * 256 + threadIdx.x;   // grid 256 -> 65536 ids
  int col = id >> 8;
  int k = id & 255;
  int h = col >> 5, d = col & 31;
  Wp[col * 256 + k] = (u16)(pk2(W[h * 8192 + k * 32 + d], 0.f) & 0xFFFFu);
}

// ---------------- MFMA GEMM + fused attn projections ------------------------
// H[n][h*32+d] = X[n,:] @ W[h,:,d] + bw[h,d], stored f16.
// 128x256 tile (all heads per block), 512 thr = 8 waves. W staged from the
// pre-packed bf16 Wp (coalesced 16B copies, no per-block transpose/convert).
__global__ __launch_bounds__(512) void k_gemm(
    const float* __restrict__ X, const u16* __restrict__ Wp,
    const float* __restrict__ bw, const float* __restrict__ A,
    __half* __restrict__ Hb, float* __restrict__ si, float* __restrict__ sj) {
  __shared__ __align__(16) u16 Xs[128 * 40];  // [row][k] stride 40
  __shared__ __align__(16) u16 Wt[256 * 40];  // [col][k] stride 40

  const int t = threadIdx.x;
  const int m0 = blockIdx.x * 128;
  const int w = t >> 6;
  const int lane = t & 63;
  const int l15 = lane & 15;
  const int quad = lane >> 4;
  const int wm = (w >> 2) * 64;   // wave row offset in block tile
  const int wn = (w & 3) * 64;    // wave col offset in block tile

  f4v acc[4][4];
#pragma unroll
  for (int i = 0; i < 4; i++)
#pragma unroll
    for (int j = 0; j < 4; j++) acc[i][j] = (f4v){0.f, 0.f, 0.f, 0.f};

  const int wcol = t >> 2;        // 0..127 (W staging)
  const int wpart = t & 3;        // 16B part of a 32-k row

  for (int k0 = 0; k0 < FIN; k0 += 32) {
    // stage X tile: 128 rows x 32 k (fp32 -> bf16), read once globally -> NT
#pragma unroll
    for (int p = 0; p < 2; p++) {
      int row = p * 64 + (t >> 3);
      int f4 = t & 7;
      int node = m0 + row;
      fx4 xv = (fx4){0.f, 0.f, 0.f, 0.f};
      if (node < N_NODES)
        xv = __builtin_nontemporal_load((const fx4*)&X[node * FIN + k0 + f4 * 4]);
      u32* dst = (u32*)&Xs[row * 40 + f4 * 4];
      dst[0] = pk2(xv[0], xv[1]);
      dst[1] = pk2(xv[2], xv[3]);
    }
    // stage W tile from pre-packed Wp: 2x coalesced 16B copies per thread
#pragma unroll
    for (int c2 = 0; c2 < 2; c2++) {
      int cc = wcol + c2 * 128;
      *(fx4*)&Wt[cc * 40 + wpart * 8] =
          *(const fx4*)&Wp[cc * 256 + k0 + wpart * 8];
    }
    __syncthreads();
    s8v af[4], bf[4];
#pragma unroll
    for (int mi = 0; mi < 4; mi++)
      af[mi] = *(const s8v*)&Xs[(wm + mi * 16 + l15) * 40 + quad * 8];
#pragma unroll
    for (int ni = 0; ni < 4; ni++)
      bf[ni] = *(const s8v*)&Wt[(wn + ni * 16 + l15) * 40 + quad * 8];
#pragma unroll
    for (int mi = 0; mi < 4; mi++)
#pragma unroll
      for (int ni = 0; ni < 4; ni++)
        acc[mi][ni] = __builtin_amdgcn_mfma_f32_16x16x32_bf16(af[mi], bf[ni], acc[mi][ni], 0, 0, 0);
    __syncthreads();
  }

  // epilogue: bias, store f16 H, fused si/sj
  const int head0 = wn >> 5;
  const int head1 = head0 + 1;
  float c1a0 = A[head0 * 64 + l15],      c1a1 = A[head0 * 64 + 16 + l15];
  float c2a0 = A[head0 * 64 + 32 + l15], c2a1 = A[head0 * 64 + 48 + l15];
  float c1b0 = A[head1 * 64 + l15],      c1b1 = A[head1 * 64 + 16 + l15];
  float c2b0 = A[head1 * 64 + 32 + l15], c2b1 = A[head1 * 64 + 48 + l15];

#pragma unroll
  for (int mi = 0; mi < 4; mi++) {
#pragma unroll
    for (int ni = 0; ni < 4; ni++) {
      float b = bw[wn + ni * 16 + l15];
#pragma unroll
      for (int r = 0; r < 4; r++) acc[mi][ni][r] += b;
    }
    const int rbase = m0 + wm + mi * 16 + quad * 4;
#pragma unroll
    for (int r = 0; r < 4; r++) {
      int node = rbase + r;
      if (node < N_NODES) {
#pragma unroll
        for (int ni = 0; ni < 4; ni++) {
          int col = wn + ni * 16 + l15;
          Hb[node * HID + col] = __float2half_rn(acc[mi][ni][r]);
        }
      }
    }
    float s1a[4], s2a[4], s1b[4], s2b[4];
#pragma unroll
    for (int r = 0; r < 4; r++) {
      s1a[r] = acc[mi][0][r] * c1a0 + acc[mi][1][r] * c1a1;
      s2a[r] = acc[mi][0][r] * c2a0 + acc[mi][1][r] * c2a1;
      s1b[r] = acc[mi][2][r] * c1b0 + acc[mi][3][r] * c1b1;
      s2b[r] = acc[mi][2][r] * c2b0 + acc[mi][3][r] * c2b1;
    }
#pragma unroll
    for (int off = 1; off <= 8; off <<= 1) {
#pragma unroll
      for (int r = 0; r < 4; r++) {
        s1a[r] += __shfl_xor(s1a[r], off);
        s2a[r] += __shfl_xor(s2a[r], off);
        s1b[r] += __shfl_xor(s1b[r], off);
        s2b[r] += __shfl_xor(s2b[r], off);
      }
    }
    if (l15 == 0) {
#pragma unroll
      for (int r = 0; r < 4; r++) {
        int node = rbase + r;
        if (node < N_NODES) {
          si[node * HEADS + head0] = s1a[r];
          sj[node * HEADS + head0] = s2a[r];
          si[node * HEADS + head1] = s1b[r];
          sj[node * HEADS + head1] = s2b[r];
        }
      }
    }
  }
}

// ---------------- counting sort of edges by target ----------------
// hist also emits rank[e] (the atomicAdd return) so scatter needs no atomic.
__global__ void k_hist(const int* __restrict__ tgt, int* __restrict__ cnt,
                       int* __restrict__ rank) {
  int e = blockIdx.x * 256 + threadIdx.x;
  if (e < N_EDGES) rank[e] = atomicAdd(&cnt[tgt[e]], 1);
}

__global__ __launch_bounds__(256) void k_scan1(const int* __restrict__ cnt,
    int* __restrict__ excl, int* __restrict__ bsum) {
  __shared__ int s[256];
  const int t = threadIdx.x;
  const int i = blockIdx.x * 256 + t;
  int v = (i < N_NODES) ? cnt[i] : 0;
  s[t] = v;
  __syncthreads();
  int x = v;
  for (int off = 1; off < 256; off <<= 1) {
    int y = (t >= off) ? s[t - off] : 0;
    __syncthreads();
    x += y;
    s[t] = x;
    __syncthreads();
  }
  if (i < N_NODES) excl[i] = x - v;
  if (t == 255) bsum[blockIdx.x] = x;
}

__global__ __launch_bounds__(256) void k_scan2(const int* __restrict__ bsum,
                                               int* __restrict__ boff) {
  __shared__ int s[256];
  const int t = threadIdx.x;
  int v = (t < 196) ? bsum[t] : 0;
  s[t] = v;
  __syncthreads();
  int x = v;
  for (int off = 1; off < 256; off <<= 1) {
    int y = (t >= off) ? s[t - off] : 0;
    __syncthreads();
    x += y;
    s[t] = x;
    __syncthreads();
  }
  if (t < 196) boff[t] = x - v;
}

__global__ void k_scan3(const int* __restrict__ excl, const int* __restrict__ boff,
                        int* __restrict__ rowptr) {
  int i = blockIdx.x * 256 + threadIdx.x;
  if (i < N_NODES) rowptr[i] = excl[i] + boff[blockIdx.x];
}

__global__ void k_scatter(const int* __restrict__ tgt, const int* __restrict__ src,
                          const int* __restrict__ rowptr, const int* __restrict__ rank,
                          int* __restrict__ sortedSrc) {
  int e = blockIdx.x * 256 + threadIdx.x;
  if (e < N_EDGES) sortedSrc[rowptr[tgt[e]] + rank[e]] = src[e];
}

// ---------------- degree-balanced node order (descending degree) ------------
__global__ void k_dhist(const int* __restrict__ cnt, int* __restrict__ dcnt) {
  int n = blockIdx.x * 256 + threadIdx.x;
  if (n < N_NODES) atomicAdd(&dcnt[255 - min(cnt[n], 255)], 1);
}

__global__ __launch_bounds__(256) void k_dscan(const int* __restrict__ dcnt,
                                               int* __restrict__ dcur) {
  __shared__ int s[256];
  const int t = threadIdx.x;
  int v = dcnt[t];
  s[t] = v;
  __syncthreads();
  int x = v;
  for (int off = 1; off < 256; off <<= 1) {
    int y = (t >= off) ? s[t - off] : 0;
    __syncthreads();
    x += y;
    s[t] = x;
    __syncthreads();
  }
  dcur[t] = x - v;
}

__global__ void k_dscatter(const int* __restrict__ cnt, int* __restrict__ dcur,
                           int* __restrict__ perm) {
  int n = blockIdx.x * 256 + threadIdx.x;
  if (n < N_NODES) {
    int pos = atomicAdd(&dcur[255 - min(cnt[n], 255)], 1);
    perm[pos] = n;
  }
}

// ---------------- fused: softmax-agg + skip + ELU + LN + head-mean + Wout + ELU
// Wave-per-node, zero LDS/barriers. Block's 4 nodes come from the degree-sorted
// perm -> near-equal work per wave, no block-tail waste (R4: occupancy 61%).
__global__ __launch_bounds__(256) void k_fused(
    const __half* __restrict__ Hb, const float* __restrict__ si,
    const float* __restrict__ sj, const float* __restrict__ ba,
    const float* __restrict__ gamma, const float* __restrict__ beta,
    const float* __restrict__ Wout, const float* __restrict__ bout,
    const int* __restrict__ rowptr, const int* __restrict__ cnt,
    const int* __restrict__ sortedSrc, const int* __restrict__ perm,
    float* __restrict__ out) {
  const int t = threadIdx.x;
  const int lane = t & 63;
  const int n = perm[blockIdx.x * 4 + (t >> 6)];  // grid 12500 * 4 nodes exact
  const int cg = lane & 31;                  // col group: cols cg*8 .. cg*8+7
  const int es = lane >> 5;                  // edge-slot stride lane 0/1
  const int hh = cg >> 2;                    // head of this col group
  const int start = rowptr[n];
  const int deg = cnt[n];

  const float sb = si[n * HEADS + hh] + ba[hh];
  const char* hbBase = (const char*)Hb + 16 * cg;
  const int* ss = sortedSrc + start;

  float acc[8] = {0.f, 0.f, 0.f, 0.f, 0.f, 0.f, 0.f, 0.f};
  float den = 0.f;
#pragma unroll 4
  for (int slot = es; slot < deg; slot += 2) {
    int s = __builtin_nontemporal_load(ss + slot);  // streamed, read-once
    float e = sb + sj[s * HEADS + hh];
    e = (e >= 0.f) ? e : 0.2f * e;
    float exv = __expf(e);
    float4 hb4 = *(const float4*)(hbBase + (size_t)s * (HID * 2));
    const __half2* hp = (const __half2*)&hb4;
#pragma unroll
    for (int d = 0; d < 4; d++) {
      acc[2 * d]     += exv * __low2float(hp[d]);   // v_fma_mix_f32
      acc[2 * d + 1] += exv * __high2float(hp[d]);
    }
    den += exv;
  }
#pragma unroll
  for (int j = 0; j < 8; j++) acc[j] += __shfl_xor(acc[j], 32);
  den += __shfl_xor(den, 32);

  // skip connection + ELU for this lane's 8 cols
  float4 h4 = *(const float4*)((const char*)Hb + (size_t)n * (HID * 2) + 16 * cg);
  const __half2* hq = (const __half2*)&h4;
  float inv = (deg > 0) ? __fdividef(1.f, den) : 0.f;
  float v[8], sum = 0.f, sq = 0.f;
#pragma unroll
  for (int j = 0; j < 8; j++) {
    float hv = (j & 1) ? __high2float(hq[j >> 1]) : __low2float(hq[j >> 1]);
    float x = acc[j] * inv + hv;
    x = (x > 0.f) ? x : (__expf(x) - 1.f);
    v[j] = x;
    sum += x;
    sq += x * x;
  }
  // LayerNorm over the head's 32 cols: in-lane 8 + 4-lane group (xor 1,2)
  sum += __shfl_xor(sum, 1); sq += __shfl_xor(sq, 1);
  sum += __shfl_xor(sum, 2); sq += __shfl_xor(sq, 2);
  float mu = sum * (1.f / 32.f);
  float var = sq * (1.f / 32.f) - mu * mu;
  float rstd = rsqrtf(var + 1e-5f);
  fx4 g0 = *(const fx4*)&gamma[cg * 8];
  fx4 g1 = *(const fx4*)&gamma[cg * 8 + 4];
  fx4 b0 = *(const fx4*)&beta[cg * 8];
  fx4 b1 = *(const fx4*)&beta[cg * 8 + 4];
  float m2[8];
#pragma unroll
  for (int j = 0; j < 8; j++) {
    float g = (j < 4) ? g0[j] : g1[j - 4];
    float bb = (j < 4) ? b0[j] : b1[j - 4];
    m2[j] = (v[j] - mu) * rstd * g + bb;
  }
  // head-mean: sum over heads = lanes differing in cg bits 2..4
#pragma unroll
  for (int j = 0; j < 8; j++) {
    m2[j] += __shfl_xor(m2[j], 4);
    m2[j] += __shfl_xor(m2[j], 8);
    m2[j] += __shfl_xor(m2[j], 16);
  }
  // Output projection: lane owns cols 4*lane..4*lane+3 (coalesced Wout rows)
  fx4 y = *(const fx4*)&bout[4 * lane];
#pragma unroll
  for (int q = 0; q < 4; q++) {
    float mv[8];
#pragma unroll
    for (int j = 0; j < 8; j++) mv[j] = __shfl(m2[j], q) * 0.125f;
#pragma unroll
    for (int j = 0; j < 8; j++) {
      fx4 w4 = *(const fx4*)&Wout[(q * 8 + j) * HID + 4 * lane];
      y += mv[j] * w4;
    }
  }
#pragma unroll
  for (int c = 0; c < 4; c++) y[c] = (y[c] > 0.f) ? y[c] : (__expf(y[c]) - 1.f);
  __builtin_nontemporal_store(y, (fx4*)&out[(size_t)n * HID + 4 * lane]);
}

extern "C" void kernel_launch(void* const* d_in, const int* in_sizes, int n_in,
                              void* d_out, int out_size, void* d_ws, size_t ws_size,
                              hipStream_t stream) {
  const float* X     = (const float*)d_in[0];
  const int*   EI    = (const int*)d_in[1];
  const float* W     = (const float*)d_in[2];
  const float* bw    = (const float*)d_in[3];
  const float* A     = (const float*)d_in[4];
  const float* ba    = (const float*)d_in[5];
  const float* gamma = (const float*)d_in[6];
  const float* beta  = (const float*)d_in[7];
  const float* Wout  = (const float*)d_in[8];
  const float* bout  = (const float*)d_in[9];
  float* out = (float*)d_out;
  const int* tgt = EI;
  const int* src = EI + N_EDGES;

  char* ws = (char*)d_ws;
  size_t off = 0;
  auto alloc = [&](size_t bytes) -> void* {
    void* p = ws + off;
    off += bytes;
    off = (off + 255) & ~(size_t)255;
    return p;
  };
  __half* Hb       = (__half*)alloc((size_t)N_NODES * HID * 2);
  float* si        = (float*)alloc((size_t)N_NODES * HEADS * 4);
  float* sj        = (float*)alloc((size_t)N_NODES * HEADS * 4);
  int*   cnt       = (int*)  alloc((size_t)N_NODES * 4);
  int*   excl      = (int*)  alloc((size_t)N_NODES * 4);
  int*   bsum      = (int*)  alloc(256 * 4);
  int*   boff      = (int*)  alloc(256 * 4);
  int*   rowptr    = (int*)  alloc((size_t)N_NODES * 4);
  int*   rank      = (int*)  alloc((size_t)N_EDGES * 4);
  int*   sortedSrc = (int*)  alloc((size_t)N_EDGES * 4);
  int*   dcnt      = (int*)  alloc(256 * 4);
  int*   dcur      = (int*)  alloc(256 * 4);
  int*   perm      = (int*)  alloc((size_t)N_NODES * 4);
  u16*   Wp        = (u16*)  alloc((size_t)HID * FIN * 2);

  hipMemsetAsync(cnt, 0, (size_t)N_NODES * 4, stream);
  hipMemsetAsync(dcnt, 0, 256 * 4, stream);
  k_prepw<<<256, 256, 0, stream>>>(W, Wp);
  k_hist<<<(N_EDGES + 255) / 256, 256, 0, stream>>>(tgt, cnt, rank);
  k_scan1<<<196, 256, 0, stream>>>(cnt, excl, bsum);
  k_scan2<<<1, 256, 0, stream>>>(bsum, boff);
  k_scan3<<<196, 256, 0, stream>>>(excl, boff, rowptr);
  k_scatter<<<(N_EDGES + 255) / 256, 256, 0, stream>>>(tgt, src, rowptr, rank, sortedSrc);
  k_dhist<<<196, 256, 0, stream>>>(cnt, dcnt);
  k_dscan<<<1, 256, 0, stream>>>(dcnt, dcur);
  k_dscatter<<<196, 256, 0, stream>>>(cnt, dcur, perm);
  k_gemm<<<(N_NODES + 127) / 128, 512, 0, stream>>>(X, Wp, bw, A, Hb, si, sj);
  k_fused<<<(N_NODES + 3) / 4, 256, 0, stream>>>(Hb, si, sj, ba, gamma, beta,
                                                 Wout, bout, rowptr, cnt,
                                                 sortedSrc, perm, out);
}

// Round 6
// 506.362 us; speedup vs baseline: 1.1624x; 1.1624x over previous
//
#include <hip/hip_runtime.h>
#include <hip/hip_bf16.h>
#include <hip/hip_fp16.h>

#define N_NODES 50000
#define N_EDGES 1600000
#define HEADS 8
#define HD 32
#define FIN 256
#define HID 256

typedef unsigned short u16;
typedef unsigned int u32;

typedef short s8v __attribute__((ext_vector_type(8)));   // 8 bf16 (4 VGPRs)
typedef float f4v __attribute__((ext_vector_type(4)));   // 4 fp32 acc
typedef float fx4 __attribute__((ext_vector_type(4)));   // clang vec (NT-able)

// pack 2 fp32 -> 2 bf16 (RNE) in one u32; lowers to v_cvt_pk_bf16_f32 on gfx950
__device__ __forceinline__ u32 pk2(float lo, float hi) {
  __hip_bfloat162 b = __float22bfloat162_rn(make_float2(lo, hi));
  union { __hip_bfloat162 b2; u32 u; } c;
  c.b2 = b;
  return c.u;
}

// ---------------- one-time W pre-pack: Wp[col*256+k] = bf16(W[h][k][d]) -----
__global__ __launch_bounds__(256) void k_prepw(const float* __restrict__ W,
                                               u16* __restrict__ Wp) {
  int id = blockIdx.x * 256 + threadIdx.x;   // grid 256 -> 65536 ids
  int col = id >> 8;
  int k = id & 255;
  int h = col >> 5, d = col & 31;
  Wp[col * 256 + k] = (u16)(pk2(W[h * 8192 + k * 32 + d], 0.f) & 0xFFFFu);
}

// ---------------- MFMA GEMM + fused attn projections ------------------------
// H[n][h*32+d] = X[n,:] @ W[h,:,d] + bw[h,d], stored f16.
// Round 6 geometry: 64x256 tile, 256 thr = 4 waves (1 row-group x 4 col-groups)
// -> grid 782 = ~3 blocks/CU (R4's 392x512 was 1.5 blocks/CU with a 2x tail
// imbalance). X still fetched exactly once; W staged from pre-packed bf16 Wp.
__global__ __launch_bounds__(256) void k_gemm(
    const float* __restrict__ X, const u16* __restrict__ Wp,
    const float* __restrict__ bw, const float* __restrict__ A,
    __half* __restrict__ Hb, float* __restrict__ si, float* __restrict__ sj) {
  __shared__ __align__(16) u16 Xs[64 * 40];   // [row][k] stride 40
  __shared__ __align__(16) u16 Wt[256 * 40];  // [col][k] stride 40

  const int t = threadIdx.x;
  const int m0 = blockIdx.x * 64;
  const int w = t >> 6;
  const int lane = t & 63;
  const int l15 = lane & 15;
  const int quad = lane >> 4;
  const int wn = w * 64;          // wave col offset in block tile

  f4v acc[4][4];
#pragma unroll
  for (int i = 0; i < 4; i++)
#pragma unroll
    for (int j = 0; j < 4; j++) acc[i][j] = (f4v){0.f, 0.f, 0.f, 0.f};

  const int srow = t >> 2;        // 0..63 (X row / W col staging)
  const int spart = t & 3;        // 8-k quarter

  for (int k0 = 0; k0 < FIN; k0 += 32) {
    // stage X tile: 64 rows x 32 k (fp32 -> bf16), read once globally -> NT
    {
      int node = m0 + srow;
      fx4 xa = (fx4){0.f, 0.f, 0.f, 0.f}, xb = xa;
      if (node < N_NODES) {
        const float* xp = &X[node * FIN + k0 + spart * 8];
        xa = __builtin_nontemporal_load((const fx4*)xp);
        xb = __builtin_nontemporal_load((const fx4*)(xp + 4));
      }
      u32* dst = (u32*)&Xs[srow * 40 + spart * 8];
      dst[0] = pk2(xa[0], xa[1]);
      dst[1] = pk2(xa[2], xa[3]);
      dst[2] = pk2(xb[0], xb[1]);
      dst[3] = pk2(xb[2], xb[3]);
    }
    // stage W tile from pre-packed Wp: coalesced 16B copies
#pragma unroll
    for (int c2 = 0; c2 < 4; c2++) {
      int cc = srow + c2 * 64;
      *(fx4*)&Wt[cc * 40 + spart * 8] =
          *(const fx4*)&Wp[cc * 256 + k0 + spart * 8];
    }
    __syncthreads();
    s8v af[4], bf[4];
#pragma unroll
    for (int mi = 0; mi < 4; mi++)
      af[mi] = *(const s8v*)&Xs[(mi * 16 + l15) * 40 + quad * 8];
#pragma unroll
    for (int ni = 0; ni < 4; ni++)
      bf[ni] = *(const s8v*)&Wt[(wn + ni * 16 + l15) * 40 + quad * 8];
#pragma unroll
    for (int mi = 0; mi < 4; mi++)
#pragma unroll
      for (int ni = 0; ni < 4; ni++)
        acc[mi][ni] = __builtin_amdgcn_mfma_f32_16x16x32_bf16(af[mi], bf[ni], acc[mi][ni], 0, 0, 0);
    __syncthreads();
  }

  // epilogue: bias, store f16 H, fused si/sj
  const int head0 = wn >> 5;
  const int head1 = head0 + 1;
  float c1a0 = A[head0 * 64 + l15],      c1a1 = A[head0 * 64 + 16 + l15];
  float c2a0 = A[head0 * 64 + 32 + l15], c2a1 = A[head0 * 64 + 48 + l15];
  float c1b0 = A[head1 * 64 + l15],      c1b1 = A[head1 * 64 + 16 + l15];
  float c2b0 = A[head1 * 64 + 32 + l15], c2b1 = A[head1 * 64 + 48 + l15];

#pragma unroll
  for (int mi = 0; mi < 4; mi++) {
#pragma unroll
    for (int ni = 0; ni < 4; ni++) {
      float b = bw[wn + ni * 16 + l15];
#pragma unroll
      for (int r = 0; r < 4; r++) acc[mi][ni][r] += b;
    }
    const int rbase = m0 + mi * 16 + quad * 4;
#pragma unroll
    for (int r = 0; r < 4; r++) {
      int node = rbase + r;
      if (node < N_NODES) {
#pragma unroll
        for (int ni = 0; ni < 4; ni++) {
          int col = wn + ni * 16 + l15;
          Hb[node * HID + col] = __float2half_rn(acc[mi][ni][r]);
        }
      }
    }
    float s1a[4], s2a[4], s1b[4], s2b[4];
#pragma unroll
    for (int r = 0; r < 4; r++) {
      s1a[r] = acc[mi][0][r] * c1a0 + acc[mi][1][r] * c1a1;
      s2a[r] = acc[mi][0][r] * c2a0 + acc[mi][1][r] * c2a1;
      s1b[r] = acc[mi][2][r] * c1b0 + acc[mi][3][r] * c1b1;
      s2b[r] = acc[mi][2][r] * c2b0 + acc[mi][3][r] * c2b1;
    }
#pragma unroll
    for (int off = 1; off <= 8; off <<= 1) {
#pragma unroll
      for (int r = 0; r < 4; r++) {
        s1a[r] += __shfl_xor(s1a[r], off);
        s2a[r] += __shfl_xor(s2a[r], off);
        s1b[r] += __shfl_xor(s1b[r], off);
        s2b[r] += __shfl_xor(s2b[r], off);
      }
    }
    if (l15 == 0) {
#pragma unroll
      for (int r = 0; r < 4; r++) {
        int node = rbase + r;
        if (node < N_NODES) {
          si[node * HEADS + head0] = s1a[r];
          sj[node * HEADS + head0] = s2a[r];
          si[node * HEADS + head1] = s1b[r];
          sj[node * HEADS + head1] = s2b[r];
        }
      }
    }
  }
}

// ---------------- counting sort of edges by target (R4 version) -------------
__global__ void k_hist(const int* __restrict__ tgt, int* __restrict__ cnt) {
  int e = blockIdx.x * 256 + threadIdx.x;
  if (e < N_EDGES) atomicAdd(&cnt[tgt[e]], 1);
}

__global__ __launch_bounds__(256) void k_scan1(const int* __restrict__ cnt,
    int* __restrict__ excl, int* __restrict__ bsum) {
  __shared__ int s[256];
  const int t = threadIdx.x;
  const int i = blockIdx.x * 256 + t;
  int v = (i < N_NODES) ? cnt[i] : 0;
  s[t] = v;
  __syncthreads();
  int x = v;
  for (int off = 1; off < 256; off <<= 1) {
    int y = (t >= off) ? s[t - off] : 0;
    __syncthreads();
    x += y;
    s[t] = x;
    __syncthreads();
  }
  if (i < N_NODES) excl[i] = x - v;
  if (t == 255) bsum[blockIdx.x] = x;
}

__global__ __launch_bounds__(256) void k_scan2(const int* __restrict__ bsum,
                                               int* __restrict__ boff) {
  __shared__ int s[256];
  const int t = threadIdx.x;
  int v = (t < 196) ? bsum[t] : 0;
  s[t] = v;
  __syncthreads();
  int x = v;
  for (int off = 1; off < 256; off <<= 1) {
    int y = (t >= off) ? s[t - off] : 0;
    __syncthreads();
    x += y;
    s[t] = x;
    __syncthreads();
  }
  if (t < 196) boff[t] = x - v;
}

__global__ void k_scan3(const int* __restrict__ excl, const int* __restrict__ boff,
                        int* __restrict__ rowptr, int* __restrict__ cursor) {
  int i = blockIdx.x * 256 + threadIdx.x;
  if (i < N_NODES) {
    int v = excl[i] + boff[blockIdx.x];
    rowptr[i] = v;
    cursor[i] = v;
  }
}

__global__ void k_scatter(const int* __restrict__ tgt, const int* __restrict__ src,
                          int* __restrict__ cursor, int* __restrict__ sortedSrc) {
  int e = blockIdx.x * 256 + threadIdx.x;
  if (e < N_EDGES) {
    int tg = tgt[e];
    int pos = atomicAdd(&cursor[tg], 1);
    sortedSrc[pos] = src[e];
  }
}

// ---------------- fused: softmax-agg + skip + ELU + LN + head-mean + Wout + ELU
// Wave-per-node, zero LDS/barriers (R4 version -- degree perm reverted: R5
// showed occupancy 61->73% with ZERO time gain; k_fused is gather-BW-bound).
__global__ __launch_bounds__(256) void k_fused(
    const __half* __restrict__ Hb, const float* __restrict__ si,
    const float* __restrict__ sj, const float* __restrict__ ba,
    const float* __restrict__ gamma, const float* __restrict__ beta,
    const float* __restrict__ Wout, const float* __restrict__ bout,
    const int* __restrict__ rowptr, const int* __restrict__ cnt,
    const int* __restrict__ sortedSrc, float* __restrict__ out) {
  const int t = threadIdx.x;
  const int lane = t & 63;
  const int n = blockIdx.x * 4 + (t >> 6);   // grid = 12500, 4 nodes/block exact
  const int cg = lane & 31;                  // col group: cols cg*8 .. cg*8+7
  const int es = lane >> 5;                  // edge-slot stride lane 0/1
  const int hh = cg >> 2;                    // head of this col group
  const int start = rowptr[n];
  const int deg = cnt[n];

  const float sb = si[n * HEADS + hh] + ba[hh];
  const char* hbBase = (const char*)Hb + 16 * cg;
  const int* ss = sortedSrc + start;

  float acc[8] = {0.f, 0.f, 0.f, 0.f, 0.f, 0.f, 0.f, 0.f};
  float den = 0.f;
#pragma unroll 4
  for (int slot = es; slot < deg; slot += 2) {
    int s = __builtin_nontemporal_load(ss + slot);  // streamed, read-once
    float e = sb + sj[s * HEADS + hh];
    e = (e >= 0.f) ? e : 0.2f * e;
    float exv = __expf(e);
    float4 hb4 = *(const float4*)(hbBase + (size_t)s * (HID * 2));
    const __half2* hp = (const __half2*)&hb4;
#pragma unroll
    for (int d = 0; d < 4; d++) {
      acc[2 * d]     += exv * __low2float(hp[d]);   // v_fma_mix_f32
      acc[2 * d + 1] += exv * __high2float(hp[d]);
    }
    den += exv;
  }
#pragma unroll
  for (int j = 0; j < 8; j++) acc[j] += __shfl_xor(acc[j], 32);
  den += __shfl_xor(den, 32);

  // skip connection + ELU for this lane's 8 cols
  float4 h4 = *(const float4*)((const char*)Hb + (size_t)n * (HID * 2) + 16 * cg);
  const __half2* hq = (const __half2*)&h4;
  float inv = (deg > 0) ? __fdividef(1.f, den) : 0.f;
  float v[8], sum = 0.f, sq = 0.f;
#pragma unroll
  for (int j = 0; j < 8; j++) {
    float hv = (j & 1) ? __high2float(hq[j >> 1]) : __low2float(hq[j >> 1]);
    float x = acc[j] * inv + hv;
    x = (x > 0.f) ? x : (__expf(x) - 1.f);
    v[j] = x;
    sum += x;
    sq += x * x;
  }
  // LayerNorm over the head's 32 cols: in-lane 8 + 4-lane group (xor 1,2)
  sum += __shfl_xor(sum, 1); sq += __shfl_xor(sq, 1);
  sum += __shfl_xor(sum, 2); sq += __shfl_xor(sq, 2);
  float mu = sum * (1.f / 32.f);
  float var = sq * (1.f / 32.f) - mu * mu;
  float rstd = rsqrtf(var + 1e-5f);
  fx4 g0 = *(const fx4*)&gamma[cg * 8];
  fx4 g1 = *(const fx4*)&gamma[cg * 8 + 4];
  fx4 b0 = *(const fx4*)&beta[cg * 8];
  fx4 b1 = *(const fx4*)&beta[cg * 8 + 4];
  float m2[8];
#pragma unroll
  for (int j = 0; j < 8; j++) {
    float g = (j < 4) ? g0[j] : g1[j - 4];
    float bb = (j < 4) ? b0[j] : b1[j - 4];
    m2[j] = (v[j] - mu) * rstd * g + bb;
  }
  // head-mean: sum over heads = lanes differing in cg bits 2..4
#pragma unroll
  for (int j = 0; j < 8; j++) {
    m2[j] += __shfl_xor(m2[j], 4);
    m2[j] += __shfl_xor(m2[j], 8);
    m2[j] += __shfl_xor(m2[j], 16);
  }
  // Output projection: lane owns cols 4*lane..4*lane+3 (coalesced Wout rows)
  fx4 y = *(const fx4*)&bout[4 * lane];
#pragma unroll
  for (int q = 0; q < 4; q++) {
    float mv[8];
#pragma unroll
    for (int j = 0; j < 8; j++) mv[j] = __shfl(m2[j], q) * 0.125f;
#pragma unroll
    for (int j = 0; j < 8; j++) {
      fx4 w4 = *(const fx4*)&Wout[(q * 8 + j) * HID + 4 * lane];
      y += mv[j] * w4;
    }
  }
#pragma unroll
  for (int c = 0; c < 4; c++) y[c] = (y[c] > 0.f) ? y[c] : (__expf(y[c]) - 1.f);
  __builtin_nontemporal_store(y, (fx4*)&out[(size_t)n * HID + 4 * lane]);
}

extern "C" void kernel_launch(void* const* d_in, const int* in_sizes, int n_in,
                              void* d_out, int out_size, void* d_ws, size_t ws_size,
                              hipStream_t stream) {
  const float* X     = (const float*)d_in[0];
  const int*   EI    = (const int*)d_in[1];
  const float* W     = (const float*)d_in[2];
  const float* bw    = (const float*)d_in[3];
  const float* A     = (const float*)d_in[4];
  const float* ba    = (const float*)d_in[5];
  const float* gamma = (const float*)d_in[6];
  const float* beta  = (const float*)d_in[7];
  const float* Wout  = (const float*)d_in[8];
  const float* bout  = (const float*)d_in[9];
  float* out = (float*)d_out;
  const int* tgt = EI;
  const int* src = EI + N_EDGES;

  char* ws = (char*)d_ws;
  size_t off = 0;
  auto alloc = [&](size_t bytes) -> void* {
    void* p = ws + off;
    off += bytes;
    off = (off + 255) & ~(size_t)255;
    return p;
  };
  __half* Hb       = (__half*)alloc((size_t)N_NODES * HID * 2);
  float* si        = (float*)alloc((size_t)N_NODES * HEADS * 4);
  float* sj        = (float*)alloc((size_t)N_NODES * HEADS * 4);
  int*   cnt       = (int*)  alloc((size_t)N_NODES * 4);
  int*   excl      = (int*)  alloc((size_t)N_NODES * 4);
  int*   bsum      = (int*)  alloc(256 * 4);
  int*   boff      = (int*)  alloc(256 * 4);
  int*   rowptr    = (int*)  alloc((size_t)N_NODES * 4);
  int*   cursor    = (int*)  alloc((size_t)N_NODES * 4);
  int*   sortedSrc = (int*)  alloc((size_t)N_EDGES * 4);
  u16*   Wp        = (u16*)  alloc((size_t)HID * FIN * 2);

  hipMemsetAsync(cnt, 0, (size_t)N_NODES * 4, stream);
  k_prepw<<<256, 256, 0, stream>>>(W, Wp);
  k_hist<<<(N_EDGES + 255) / 256, 256, 0, stream>>>(tgt, cnt);
  k_scan1<<<196, 256, 0, stream>>>(cnt, excl, bsum);
  k_scan2<<<1, 256, 0, stream>>>(bsum, boff);
  k_scan3<<<196, 256, 0, stream>>>(excl, boff, rowptr, cursor);
  k_scatter<<<(N_EDGES + 255) / 256, 256, 0, stream>>>(tgt, src, cursor, sortedSrc);
  k_gemm<<<(N_NODES + 63) / 64, 256, 0, stream>>>(X, Wp, bw, A, Hb, si, sj);
  k_fused<<<(N_NODES + 3) / 4, 256, 0, stream>>>(Hb, si, sj, ba, gamma, beta,
                                                 Wout, bout, rowptr, cnt,
                                                 sortedSrc, out);
}

// Round 7
// 494.233 us; speedup vs baseline: 1.1909x; 1.0245x over previous
//
#include <hip/hip_runtime.h>
#include <hip/hip_bf16.h>
#include <hip/hip_fp16.h>

#define N_NODES 50000
#define N_EDGES 1600000
#define HEADS 8
#define HD 32
#define FIN 256
#define HID 256

typedef unsigned short u16;
typedef unsigned int u32;

typedef short s8v __attribute__((ext_vector_type(8)));   // 8 bf16 (4 VGPRs)
typedef float f4v __attribute__((ext_vector_type(4)));   // 4 fp32 acc
typedef float fx4 __attribute__((ext_vector_type(4)));   // clang vec (NT-able)

// pack 2 fp32 -> 2 bf16 (RNE) in one u32; lowers to v_cvt_pk_bf16_f32 on gfx950
__device__ __forceinline__ u32 pk2(float lo, float hi) {
  __hip_bfloat162 b = __float22bfloat162_rn(make_float2(lo, hi));
  union { __hip_bfloat162 b2; u32 u; } c;
  c.b2 = b;
  return c.u;
}

// ---------------- one-time W pre-pack: Wp[col*256+k] = bf16(W[h][k][d]) -----
__global__ __launch_bounds__(256) void k_prepw(const float* __restrict__ W,
                                               u16* __restrict__ Wp) {
  int id = blockIdx.x * 256 + threadIdx.x;   // grid 256 -> 65536 ids
  int col = id >> 8;
  int k = id & 255;
  int h = col >> 5, d = col & 31;
  Wp[col * 256 + k] = (u16)(pk2(W[h * 8192 + k * 32 + d], 0.f) & 0xFFFFu);
}

// ---------------- MFMA GEMM + fused attn projections ------------------------
// H[n][h*32+d] = X[n,:] @ W[h,:,d] + bw[h,d], stored f16.
// R4-winning geometry: 128x256 tile, 512 thr = 8 waves (X fetched once, W
// traffic halved vs 64-row tile). W staged from pre-packed bf16 Wp.
__global__ __launch_bounds__(512) void k_gemm(
    const float* __restrict__ X, const u16* __restrict__ Wp,
    const float* __restrict__ bw, const float* __restrict__ A,
    __half* __restrict__ Hb, float* __restrict__ si, float* __restrict__ sj) {
  __shared__ __align__(16) u16 Xs[128 * 40];  // [row][k] stride 40
  __shared__ __align__(16) u16 Wt[256 * 40];  // [col][k] stride 40

  const int t = threadIdx.x;
  const int m0 = blockIdx.x * 128;
  const int w = t >> 6;
  const int lane = t & 63;
  const int l15 = lane & 15;
  const int quad = lane >> 4;
  const int wm = (w >> 2) * 64;   // wave row offset in block tile
  const int wn = (w & 3) * 64;    // wave col offset in block tile

  f4v acc[4][4];
#pragma unroll
  for (int i = 0; i < 4; i++)
#pragma unroll
    for (int j = 0; j < 4; j++) acc[i][j] = (f4v){0.f, 0.f, 0.f, 0.f};

  const int wcol = t >> 2;        // 0..127 (W staging)
  const int wpart = t & 3;        // 16B part of a 32-k row

  for (int k0 = 0; k0 < FIN; k0 += 32) {
    // stage X tile: 128 rows x 32 k (fp32 -> bf16), read once globally -> NT
#pragma unroll
    for (int p = 0; p < 2; p++) {
      int row = p * 64 + (t >> 3);
      int f4 = t & 7;
      int node = m0 + row;
      fx4 xv = (fx4){0.f, 0.f, 0.f, 0.f};
      if (node < N_NODES)
        xv = __builtin_nontemporal_load((const fx4*)&X[node * FIN + k0 + f4 * 4]);
      u32* dst = (u32*)&Xs[row * 40 + f4 * 4];
      dst[0] = pk2(xv[0], xv[1]);
      dst[1] = pk2(xv[2], xv[3]);
    }
    // stage W tile from pre-packed Wp: 2x coalesced 16B copies per thread
#pragma unroll
    for (int c2 = 0; c2 < 2; c2++) {
      int cc = wcol + c2 * 128;
      *(fx4*)&Wt[cc * 40 + wpart * 8] =
          *(const fx4*)&Wp[cc * 256 + k0 + wpart * 8];
    }
    __syncthreads();
    s8v af[4], bf[4];
#pragma unroll
    for (int mi = 0; mi < 4; mi++)
      af[mi] = *(const s8v*)&Xs[(wm + mi * 16 + l15) * 40 + quad * 8];
#pragma unroll
    for (int ni = 0; ni < 4; ni++)
      bf[ni] = *(const s8v*)&Wt[(wn + ni * 16 + l15) * 40 + quad * 8];
#pragma unroll
    for (int mi = 0; mi < 4; mi++)
#pragma unroll
      for (int ni = 0; ni < 4; ni++)
        acc[mi][ni] = __builtin_amdgcn_mfma_f32_16x16x32_bf16(af[mi], bf[ni], acc[mi][ni], 0, 0, 0);
    __syncthreads();
  }

  // epilogue: bias, store f16 H, fused si/sj
  const int head0 = wn >> 5;
  const int head1 = head0 + 1;
  float c1a0 = A[head0 * 64 + l15],      c1a1 = A[head0 * 64 + 16 + l15];
  float c2a0 = A[head0 * 64 + 32 + l15], c2a1 = A[head0 * 64 + 48 + l15];
  float c1b0 = A[head1 * 64 + l15],      c1b1 = A[head1 * 64 + 16 + l15];
  float c2b0 = A[head1 * 64 + 32 + l15], c2b1 = A[head1 * 64 + 48 + l15];

#pragma unroll
  for (int mi = 0; mi < 4; mi++) {
#pragma unroll
    for (int ni = 0; ni < 4; ni++) {
      float b = bw[wn + ni * 16 + l15];
#pragma unroll
      for (int r = 0; r < 4; r++) acc[mi][ni][r] += b;
    }
    const int rbase = m0 + wm + mi * 16 + quad * 4;
#pragma unroll
    for (int r = 0; r < 4; r++) {
      int node = rbase + r;
      if (node < N_NODES) {
#pragma unroll
        for (int ni = 0; ni < 4; ni++) {
          int col = wn + ni * 16 + l15;
          Hb[node * HID + col] = __float2half_rn(acc[mi][ni][r]);
        }
      }
    }
    float s1a[4], s2a[4], s1b[4], s2b[4];
#pragma unroll
    for (int r = 0; r < 4; r++) {
      s1a[r] = acc[mi][0][r] * c1a0 + acc[mi][1][r] * c1a1;
      s2a[r] = acc[mi][0][r] * c2a0 + acc[mi][1][r] * c2a1;
      s1b[r] = acc[mi][2][r] * c1b0 + acc[mi][3][r] * c1b1;
      s2b[r] = acc[mi][2][r] * c2b0 + acc[mi][3][r] * c2b1;
    }
#pragma unroll
    for (int off = 1; off <= 8; off <<= 1) {
#pragma unroll
      for (int r = 0; r < 4; r++) {
        s1a[r] += __shfl_xor(s1a[r], off);
        s2a[r] += __shfl_xor(s2a[r], off);
        s1b[r] += __shfl_xor(s1b[r], off);
        s2b[r] += __shfl_xor(s2b[r], off);
      }
    }
    if (l15 == 0) {
#pragma unroll
      for (int r = 0; r < 4; r++) {
        int node = rbase + r;
        if (node < N_NODES) {
          si[node * HEADS + head0] = s1a[r];
          sj[node * HEADS + head0] = s2a[r];
          si[node * HEADS + head1] = s1b[r];
          sj[node * HEADS + head1] = s2b[r];
        }
      }
    }
  }
}

// ---------------- counting sort of edges by target --------------------------
// hist also emits rank[e] (the atomicAdd return): the same-address contention
// is paid ONCE here, and k_scatter becomes a pure permutation store.
__global__ void k_hist(const int* __restrict__ tgt, int* __restrict__ cnt,
                       int* __restrict__ rank) {
  int e = blockIdx.x * 256 + threadIdx.x;
  if (e < N_EDGES) {
    int tg = __builtin_nontemporal_load(tgt + e);
    rank[e] = atomicAdd(&cnt[tg], 1);
  }
}

// single-block exclusive scan of cnt -> rowptr (replaces scan1+scan2+scan3)
#define SCHUNK 49   // 1024 * 49 = 50176 >= N_NODES
__global__ __launch_bounds__(1024) void k_scan(const int* __restrict__ cnt,
                                               int* __restrict__ rowptr) {
  __shared__ int s[1024];
  const int t = threadIdx.x;
  const int base = t * SCHUNK;
  int sum = 0;
#pragma unroll 7
  for (int j = 0; j < SCHUNK; j++) {
    int i = base + j;
    sum += (i < N_NODES) ? cnt[i] : 0;
  }
  s[t] = sum;
  __syncthreads();
  int x = sum;
  for (int off = 1; off < 1024; off <<= 1) {
    int y = (t >= off) ? s[t - off] : 0;
    __syncthreads();
    x += y;
    s[t] = x;
    __syncthreads();
  }
  int run = x - sum;   // exclusive prefix of this thread's chunk
#pragma unroll 7
  for (int j = 0; j < SCHUNK; j++) {
    int i = base + j;
    if (i < N_NODES) {
      rowptr[i] = run;
      run += cnt[i];
    }
  }
}

// pure permutation store -- zero atomics
__global__ void k_scatter(const int* __restrict__ tgt, const int* __restrict__ src,
                          const int* __restrict__ rowptr, const int* __restrict__ rank,
                          int* __restrict__ sortedSrc) {
  int e = blockIdx.x * 256 + threadIdx.x;
  if (e < N_EDGES) {
    int tg = __builtin_nontemporal_load(tgt + e);
    int sc = __builtin_nontemporal_load(src + e);
    int rk = __builtin_nontemporal_load(rank + e);
    sortedSrc[rowptr[tg] + rk] = sc;
  }
}

// ---------------- fused: softmax-agg + skip + ELU + LN + head-mean + Wout + ELU
// Wave-per-node, zero LDS/barriers (unchanged control from R4/R6: k_fused is
// random-gather-BW-bound at ~3.1 TB/s; occupancy/balance changes proved null).
__global__ __launch_bounds__(256) void k_fused(
    const __half* __restrict__ Hb, const float* __restrict__ si,
    const float* __restrict__ sj, const float* __restrict__ ba,
    const float* __restrict__ gamma, const float* __restrict__ beta,
    const float* __restrict__ Wout, const float* __restrict__ bout,
    const int* __restrict__ rowptr, const int* __restrict__ cnt,
    const int* __restrict__ sortedSrc, float* __restrict__ out) {
  const int t = threadIdx.x;
  const int lane = t & 63;
  const int n = blockIdx.x * 4 + (t >> 6);   // grid = 12500, 4 nodes/block exact
  const int cg = lane & 31;                  // col group: cols cg*8 .. cg*8+7
  const int es = lane >> 5;                  // edge-slot stride lane 0/1
  const int hh = cg >> 2;                    // head of this col group
  const int start = rowptr[n];
  const int deg = cnt[n];

  const float sb = si[n * HEADS + hh] + ba[hh];
  const char* hbBase = (const char*)Hb + 16 * cg;
  const int* ss = sortedSrc + start;

  float acc[8] = {0.f, 0.f, 0.f, 0.f, 0.f, 0.f, 0.f, 0.f};
  float den = 0.f;
#pragma unroll 4
  for (int slot = es; slot < deg; slot += 2) {
    int s = __builtin_nontemporal_load(ss + slot);  // streamed, read-once
    float e = sb + sj[s * HEADS + hh];
    e = (e >= 0.f) ? e : 0.2f * e;
    float exv = __expf(e);
    float4 hb4 = *(const float4*)(hbBase + (size_t)s * (HID * 2));
    const __half2* hp = (const __half2*)&hb4;
#pragma unroll
    for (int d = 0; d < 4; d++) {
      acc[2 * d]     += exv * __low2float(hp[d]);   // v_fma_mix_f32
      acc[2 * d + 1] += exv * __high2float(hp[d]);
    }
    den += exv;
  }
#pragma unroll
  for (int j = 0; j < 8; j++) acc[j] += __shfl_xor(acc[j], 32);
  den += __shfl_xor(den, 32);

  // skip connection + ELU for this lane's 8 cols
  float4 h4 = *(const float4*)((const char*)Hb + (size_t)n * (HID * 2) + 16 * cg);
  const __half2* hq = (const __half2*)&h4;
  float inv = (deg > 0) ? __fdividef(1.f, den) : 0.f;
  float v[8], sum = 0.f, sq = 0.f;
#pragma unroll
  for (int j = 0; j < 8; j++) {
    float hv = (j & 1) ? __high2float(hq[j >> 1]) : __low2float(hq[j >> 1]);
    float x = acc[j] * inv + hv;
    x = (x > 0.f) ? x : (__expf(x) - 1.f);
    v[j] = x;
    sum += x;
    sq += x * x;
  }
  // LayerNorm over the head's 32 cols: in-lane 8 + 4-lane group (xor 1,2)
  sum += __shfl_xor(sum, 1); sq += __shfl_xor(sq, 1);
  sum += __shfl_xor(sum, 2); sq += __shfl_xor(sq, 2);
  float mu = sum * (1.f / 32.f);
  float var = sq * (1.f / 32.f) - mu * mu;
  float rstd = rsqrtf(var + 1e-5f);
  fx4 g0 = *(const fx4*)&gamma[cg * 8];
  fx4 g1 = *(const fx4*)&gamma[cg * 8 + 4];
  fx4 b0 = *(const fx4*)&beta[cg * 8];
  fx4 b1 = *(const fx4*)&beta[cg * 8 + 4];
  float m2[8];
#pragma unroll
  for (int j = 0; j < 8; j++) {
    float g = (j < 4) ? g0[j] : g1[j - 4];
    float bb = (j < 4) ? b0[j] : b1[j - 4];
    m2[j] = (v[j] - mu) * rstd * g + bb;
  }
  // head-mean: sum over heads = lanes differing in cg bits 2..4
#pragma unroll
  for (int j = 0; j < 8; j++) {
    m2[j] += __shfl_xor(m2[j], 4);
    m2[j] += __shfl_xor(m2[j], 8);
    m2[j] += __shfl_xor(m2[j], 16);
  }
  // Output projection: lane owns cols 4*lane..4*lane+3 (coalesced Wout rows)
  fx4 y = *(const fx4*)&bout[4 * lane];
#pragma unroll
  for (int q = 0; q < 4; q++) {
    float mv[8];
#pragma unroll
    for (int j = 0; j < 8; j++) mv[j] = __shfl(m2[j], q) * 0.125f;
#pragma unroll
    for (int j = 0; j < 8; j++) {
      fx4 w4 = *(const fx4*)&Wout[(q * 8 + j) * HID + 4 * lane];
      y += mv[j] * w4;
    }
  }
#pragma unroll
  for (int c = 0; c < 4; c++) y[c] = (y[c] > 0.f) ? y[c] : (__expf(y[c]) - 1.f);
  __builtin_nontemporal_store(y, (fx4*)&out[(size_t)n * HID + 4 * lane]);
}

extern "C" void kernel_launch(void* const* d_in, const int* in_sizes, int n_in,
                              void* d_out, int out_size, void* d_ws, size_t ws_size,
                              hipStream_t stream) {
  const float* X     = (const float*)d_in[0];
  const int*   EI    = (const int*)d_in[1];
  const float* W     = (const float*)d_in[2];
  const float* bw    = (const float*)d_in[3];
  const float* A     = (const float*)d_in[4];
  const float* ba    = (const float*)d_in[5];
  const float* gamma = (const float*)d_in[6];
  const float* beta  = (const float*)d_in[7];
  const float* Wout  = (const float*)d_in[8];
  const float* bout  = (const float*)d_in[9];
  float* out = (float*)d_out;
  const int* tgt = EI;
  const int* src = EI + N_EDGES;

  char* ws = (char*)d_ws;
  size_t off = 0;
  auto alloc = [&](size_t bytes) -> void* {
    void* p = ws + off;
    off += bytes;
    off = (off + 255) & ~(size_t)255;
    return p;
  };
  __half* Hb       = (__half*)alloc((size_t)N_NODES * HID * 2);
  float* si        = (float*)alloc((size_t)N_NODES * HEADS * 4);
  float* sj        = (float*)alloc((size_t)N_NODES * HEADS * 4);
  int*   cnt       = (int*)  alloc((size_t)N_NODES * 4);
  int*   rowptr    = (int*)  alloc((size_t)N_NODES * 4);
  int*   rank      = (int*)  alloc((size_t)N_EDGES * 4);
  int*   sortedSrc = (int*)  alloc((size_t)N_EDGES * 4);
  u16*   Wp        = (u16*)  alloc((size_t)HID * FIN * 2);

  hipMemsetAsync(cnt, 0, (size_t)N_NODES * 4, stream);
  k_prepw<<<256, 256, 0, stream>>>(W, Wp);
  k_hist<<<(N_EDGES + 255) / 256, 256, 0, stream>>>(tgt, cnt, rank);
  k_scan<<<1, 1024, 0, stream>>>(cnt, rowptr);
  k_scatter<<<(N_EDGES + 255) / 256, 256, 0, stream>>>(tgt, src, rowptr, rank, sortedSrc);
  k_gemm<<<(N_NODES + 127) / 128, 512, 0, stream>>>(X, Wp, bw, A, Hb, si, sj);
  k_fused<<<(N_NODES + 3) / 4, 256, 0, stream>>>(Hb, si, sj, ba, gamma, beta,
                                                 Wout, bout, rowptr, cnt,
                                                 sortedSrc, out);
}

// Round 8
// 484.709 us; speedup vs baseline: 1.2143x; 1.0197x over previous
//
#include <hip/hip_runtime.h>
#include <hip/hip_bf16.h>
#include <hip/hip_fp16.h>

#define N_NODES 50000
#define N_EDGES 1600000
#define HEADS 8
#define HD 32
#define FIN 256
#define HID 256

typedef unsigned short u16;
typedef unsigned int u32;

typedef short s8v __attribute__((ext_vector_type(8)));   // 8 bf16 (4 VGPRs)
typedef float f4v __attribute__((ext_vector_type(4)));   // 4 fp32 acc
typedef float fx4 __attribute__((ext_vector_type(4)));   // clang vec (NT-able)

// pack 2 fp32 -> 2 bf16 (RNE) in one u32; lowers to v_cvt_pk_bf16_f32 on gfx950
__device__ __forceinline__ u32 pk2(float lo, float hi) {
  __hip_bfloat162 b = __float22bfloat162_rn(make_float2(lo, hi));
  union { __hip_bfloat162 b2; u32 u; } c;
  c.b2 = b;
  return c.u;
}

// ---------------- combo 1: W pre-pack (256 blocks) ∥ edge histogram (6250) --
// prepw: Wp[col*256+k] = bf16(W[h][k][d]).  hist: cnt/rank via atomicAdd.
// Independent ops -> one grid, hist blocks first (they dominate).
#define HIST_BLOCKS ((N_EDGES + 255) / 256)
__global__ __launch_bounds__(256) void k_preph(
    const float* __restrict__ W, u16* __restrict__ Wp,
    const int* __restrict__ tgt, int* __restrict__ cnt, int* __restrict__ rank) {
  const int b = blockIdx.x;
  if (b < HIST_BLOCKS) {
    int e = b * 256 + threadIdx.x;
    if (e < N_EDGES) {
      int tg = __builtin_nontemporal_load(tgt + e);
      rank[e] = atomicAdd(&cnt[tg], 1);
    }
  } else {
    int id = (b - HIST_BLOCKS) * 256 + threadIdx.x;  // 256 blocks -> 65536 ids
    int col = id >> 8;
    int k = id & 255;
    int h = col >> 5, d = col & 31;
    Wp[col * 256 + k] = (u16)(pk2(W[h * 8192 + k * 32 + d], 0.f) & 0xFFFFu);
  }
}

// single-block exclusive scan of cnt -> rowptr
#define SCHUNK 49   // 1024 * 49 = 50176 >= N_NODES
__global__ __launch_bounds__(1024) void k_scan(const int* __restrict__ cnt,
                                               int* __restrict__ rowptr) {
  __shared__ int s[1024];
  const int t = threadIdx.x;
  const int base = t * SCHUNK;
  int sum = 0;
#pragma unroll 7
  for (int j = 0; j < SCHUNK; j++) {
    int i = base + j;
    sum += (i < N_NODES) ? cnt[i] : 0;
  }
  s[t] = sum;
  __syncthreads();
  int x = sum;
  for (int off = 1; off < 1024; off <<= 1) {
    int y = (t >= off) ? s[t - off] : 0;
    __syncthreads();
    x += y;
    s[t] = x;
    __syncthreads();
  }
  int run = x - sum;   // exclusive prefix of this thread's chunk
#pragma unroll 7
  for (int j = 0; j < SCHUNK; j++) {
    int i = base + j;
    if (i < N_NODES) {
      rowptr[i] = run;
      run += cnt[i];
    }
  }
}

// ---------------- combo 2: MFMA GEMM (391 blocks) ∥ edge scatter (3125) -----
// gemm: H = X@W + bw (f16) + fused si/sj projections -- R4-winning 128x256
// geometry, 512 thr = 8 waves, W staged from pre-packed bf16 Wp.
// scatter: pure permutation store (atomics already paid in k_preph).
// gemm blocks first -> they pin the CUs; scatter fills residual slots and its
// memory-system work overlaps gemm's MFMA/LDS work.
#define GEMM_BLOCKS ((N_NODES + 127) / 128)
__global__ __launch_bounds__(512) void k_gemsc(
    const float* __restrict__ X, const u16* __restrict__ Wp,
    const float* __restrict__ bw, const float* __restrict__ A,
    __half* __restrict__ Hb, float* __restrict__ si, float* __restrict__ sj,
    const int* __restrict__ tgt, const int* __restrict__ src,
    const int* __restrict__ rowptr, const int* __restrict__ rank,
    int* __restrict__ sortedSrc) {
  __shared__ __align__(16) u16 Xs[128 * 40];  // [row][k] stride 40
  __shared__ __align__(16) u16 Wt[256 * 40];  // [col][k] stride 40

  if (blockIdx.x >= GEMM_BLOCKS) {
    // ---------------- scatter branch ----------------
    int e = (blockIdx.x - GEMM_BLOCKS) * 512 + threadIdx.x;
    if (e < N_EDGES) {
      int tg = __builtin_nontemporal_load(tgt + e);
      int sc = __builtin_nontemporal_load(src + e);
      int rk = __builtin_nontemporal_load(rank + e);
      sortedSrc[rowptr[tg] + rk] = sc;
    }
    return;
  }

  // ---------------- gemm branch ----------------
  const int t = threadIdx.x;
  const int m0 = blockIdx.x * 128;
  const int w = t >> 6;
  const int lane = t & 63;
  const int l15 = lane & 15;
  const int quad = lane >> 4;
  const int wm = (w >> 2) * 64;   // wave row offset in block tile
  const int wn = (w & 3) * 64;    // wave col offset in block tile

  f4v acc[4][4];
#pragma unroll
  for (int i = 0; i < 4; i++)
#pragma unroll
    for (int j = 0; j < 4; j++) acc[i][j] = (f4v){0.f, 0.f, 0.f, 0.f};

  const int wcol = t >> 2;        // 0..127 (W staging)
  const int wpart = t & 3;        // 16B part of a 32-k row

  for (int k0 = 0; k0 < FIN; k0 += 32) {
    // stage X tile: 128 rows x 32 k (fp32 -> bf16), read once globally -> NT
#pragma unroll
    for (int p = 0; p < 2; p++) {
      int row = p * 64 + (t >> 3);
      int f4 = t & 7;
      int node = m0 + row;
      fx4 xv = (fx4){0.f, 0.f, 0.f, 0.f};
      if (node < N_NODES)
        xv = __builtin_nontemporal_load((const fx4*)&X[node * FIN + k0 + f4 * 4]);
      u32* dst = (u32*)&Xs[row * 40 + f4 * 4];
      dst[0] = pk2(xv[0], xv[1]);
      dst[1] = pk2(xv[2], xv[3]);
    }
    // stage W tile from pre-packed Wp: 2x coalesced 16B copies per thread
#pragma unroll
    for (int c2 = 0; c2 < 2; c2++) {
      int cc = wcol + c2 * 128;
      *(fx4*)&Wt[cc * 40 + wpart * 8] =
          *(const fx4*)&Wp[cc * 256 + k0 + wpart * 8];
    }
    __syncthreads();
    s8v af[4], bf[4];
#pragma unroll
    for (int mi = 0; mi < 4; mi++)
      af[mi] = *(const s8v*)&Xs[(wm + mi * 16 + l15) * 40 + quad * 8];
#pragma unroll
    for (int ni = 0; ni < 4; ni++)
      bf[ni] = *(const s8v*)&Wt[(wn + ni * 16 + l15) * 40 + quad * 8];
#pragma unroll
    for (int mi = 0; mi < 4; mi++)
#pragma unroll
      for (int ni = 0; ni < 4; ni++)
        acc[mi][ni] = __builtin_amdgcn_mfma_f32_16x16x32_bf16(af[mi], bf[ni], acc[mi][ni], 0, 0, 0);
    __syncthreads();
  }

  // epilogue: bias, store f16 H, fused si/sj
  const int head0 = wn >> 5;
  const int head1 = head0 + 1;
  float c1a0 = A[head0 * 64 + l15],      c1a1 = A[head0 * 64 + 16 + l15];
  float c2a0 = A[head0 * 64 + 32 + l15], c2a1 = A[head0 * 64 + 48 + l15];
  float c1b0 = A[head1 * 64 + l15],      c1b1 = A[head1 * 64 + 16 + l15];
  float c2b0 = A[head1 * 64 + 32 + l15], c2b1 = A[head1 * 64 + 48 + l15];

#pragma unroll
  for (int mi = 0; mi < 4; mi++) {
#pragma unroll
    for (int ni = 0; ni < 4; ni++) {
      float b = bw[wn + ni * 16 + l15];
#pragma unroll
      for (int r = 0; r < 4; r++) acc[mi][ni][r] += b;
    }
    const int rbase = m0 + wm + mi * 16 + quad * 4;
#pragma unroll
    for (int r = 0; r < 4; r++) {
      int node = rbase + r;
      if (node < N_NODES) {
#pragma unroll
        for (int ni = 0; ni < 4; ni++) {
          int col = wn + ni * 16 + l15;
          Hb[node * HID + col] = __float2half_rn(acc[mi][ni][r]);
        }
      }
    }
    float s1a[4], s2a[4], s1b[4], s2b[4];
#pragma unroll
    for (int r = 0; r < 4; r++) {
      s1a[r] = acc[mi][0][r] * c1a0 + acc[mi][1][r] * c1a1;
      s2a[r] = acc[mi][0][r] * c2a0 + acc[mi][1][r] * c2a1;
      s1b[r] = acc[mi][2][r] * c1b0 + acc[mi][3][r] * c1b1;
      s2b[r] = acc[mi][2][r] * c2b0 + acc[mi][3][r] * c2b1;
    }
#pragma unroll
    for (int off = 1; off <= 8; off <<= 1) {
#pragma unroll
      for (int r = 0; r < 4; r++) {
        s1a[r] += __shfl_xor(s1a[r], off);
        s2a[r] += __shfl_xor(s2a[r], off);
        s1b[r] += __shfl_xor(s1b[r], off);
        s2b[r] += __shfl_xor(s2b[r], off);
      }
    }
    if (l15 == 0) {
#pragma unroll
      for (int r = 0; r < 4; r++) {
        int node = rbase + r;
        if (node < N_NODES) {
          si[node * HEADS + head0] = s1a[r];
          sj[node * HEADS + head0] = s2a[r];
          si[node * HEADS + head1] = s1b[r];
          sj[node * HEADS + head1] = s2b[r];
        }
      }
    }
  }
}

// ---------------- fused: softmax-agg + skip + ELU + LN + head-mean + Wout + ELU
// Wave-per-node, zero LDS/barriers (unchanged control since R4).
__global__ __launch_bounds__(256) void k_fused(
    const __half* __restrict__ Hb, const float* __restrict__ si,
    const float* __restrict__ sj, const float* __restrict__ ba,
    const float* __restrict__ gamma, const float* __restrict__ beta,
    const float* __restrict__ Wout, const float* __restrict__ bout,
    const int* __restrict__ rowptr, const int* __restrict__ cnt,
    const int* __restrict__ sortedSrc, float* __restrict__ out) {
  const int t = threadIdx.x;
  const int lane = t & 63;
  const int n = blockIdx.x * 4 + (t >> 6);   // grid = 12500, 4 nodes/block exact
  const int cg = lane & 31;                  // col group: cols cg*8 .. cg*8+7
  const int es = lane >> 5;                  // edge-slot stride lane 0/1
  const int hh = cg >> 2;                    // head of this col group
  const int start = rowptr[n];
  const int deg = cnt[n];

  const float sb = si[n * HEADS + hh] + ba[hh];
  const char* hbBase = (const char*)Hb + 16 * cg;
  const int* ss = sortedSrc + start;

  float acc[8] = {0.f, 0.f, 0.f, 0.f, 0.f, 0.f, 0.f, 0.f};
  float den = 0.f;
#pragma unroll 4
  for (int slot = es; slot < deg; slot += 2) {
    int s = __builtin_nontemporal_load(ss + slot);  // streamed, read-once
    float e = sb + sj[s * HEADS + hh];
    e = (e >= 0.f) ? e : 0.2f * e;
    float exv = __expf(e);
    float4 hb4 = *(const float4*)(hbBase + (size_t)s * (HID * 2));
    const __half2* hp = (const __half2*)&hb4;
#pragma unroll
    for (int d = 0; d < 4; d++) {
      acc[2 * d]     += exv * __low2float(hp[d]);   // v_fma_mix_f32
      acc[2 * d + 1] += exv * __high2float(hp[d]);
    }
    den += exv;
  }
#pragma unroll
  for (int j = 0; j < 8; j++) acc[j] += __shfl_xor(acc[j], 32);
  den += __shfl_xor(den, 32);

  // skip connection + ELU for this lane's 8 cols
  float4 h4 = *(const float4*)((const char*)Hb + (size_t)n * (HID * 2) + 16 * cg);
  const __half2* hq = (const __half2*)&h4;
  float inv = (deg > 0) ? __fdividef(1.f, den) : 0.f;
  float v[8], sum = 0.f, sq = 0.f;
#pragma unroll
  for (int j = 0; j < 8; j++) {
    float hv = (j & 1) ? __high2float(hq[j >> 1]) : __low2float(hq[j >> 1]);
    float x = acc[j] * inv + hv;
    x = (x > 0.f) ? x : (__expf(x) - 1.f);
    v[j] = x;
    sum += x;
    sq += x * x;
  }
  // LayerNorm over the head's 32 cols: in-lane 8 + 4-lane group (xor 1,2)
  sum += __shfl_xor(sum, 1); sq += __shfl_xor(sq, 1);
  sum += __shfl_xor(sum, 2); sq += __shfl_xor(sq, 2);
  float mu = sum * (1.f / 32.f);
  float var = sq * (1.f / 32.f) - mu * mu;
  float rstd = rsqrtf(var + 1e-5f);
  fx4 g0 = *(const fx4*)&gamma[cg * 8];
  fx4 g1 = *(const fx4*)&gamma[cg * 8 + 4];
  fx4 b0 = *(const fx4*)&beta[cg * 8];
  fx4 b1 = *(const fx4*)&beta[cg * 8 + 4];
  float m2[8];
#pragma unroll
  for (int j = 0; j < 8; j++) {
    float g = (j < 4) ? g0[j] : g1[j - 4];
    float bb = (j < 4) ? b0[j] : b1[j - 4];
    m2[j] = (v[j] - mu) * rstd * g + bb;
  }
  // head-mean: sum over heads = lanes differing in cg bits 2..4
#pragma unroll
  for (int j = 0; j < 8; j++) {
    m2[j] += __shfl_xor(m2[j], 4);
    m2[j] += __shfl_xor(m2[j], 8);
    m2[j] += __shfl_xor(m2[j], 16);
  }
  // Output projection: lane owns cols 4*lane..4*lane+3 (coalesced Wout rows)
  fx4 y = *(const fx4*)&bout[4 * lane];
#pragma unroll
  for (int q = 0; q < 4; q++) {
    float mv[8];
#pragma unroll
    for (int j = 0; j < 8; j++) mv[j] = __shfl(m2[j], q) * 0.125f;
#pragma unroll
    for (int j = 0; j < 8; j++) {
      fx4 w4 = *(const fx4*)&Wout[(q * 8 + j) * HID + 4 * lane];
      y += mv[j] * w4;
    }
  }
#pragma unroll
  for (int c = 0; c < 4; c++) y[c] = (y[c] > 0.f) ? y[c] : (__expf(y[c]) - 1.f);
  __builtin_nontemporal_store(y, (fx4*)&out[(size_t)n * HID + 4 * lane]);
}

extern "C" void kernel_launch(void* const* d_in, const int* in_sizes, int n_in,
                              void* d_out, int out_size, void* d_ws, size_t ws_size,
                              hipStream_t stream) {
  const float* X     = (const float*)d_in[0];
  const int*   EI    = (const int*)d_in[1];
  const float* W     = (const float*)d_in[2];
  const float* bw    = (const float*)d_in[3];
  const float* A     = (const float*)d_in[4];
  const float* ba    = (const float*)d_in[5];
  const float* gamma = (const float*)d_in[6];
  const float* beta  = (const float*)d_in[7];
  const float* Wout  = (const float*)d_in[8];
  const float* bout  = (const float*)d_in[9];
  float* out = (float*)d_out;
  const int* tgt = EI;
  const int* src = EI + N_EDGES;

  char* ws = (char*)d_ws;
  size_t off = 0;
  auto alloc = [&](size_t bytes) -> void* {
    void* p = ws + off;
    off += bytes;
    off = (off + 255) & ~(size_t)255;
    return p;
  };
  __half* Hb       = (__half*)alloc((size_t)N_NODES * HID * 2);
  float* si        = (float*)alloc((size_t)N_NODES * HEADS * 4);
  float* sj        = (float*)alloc((size_t)N_NODES * HEADS * 4);
  int*   cnt       = (int*)  alloc((size_t)N_NODES * 4);
  int*   rowptr    = (int*)  alloc((size_t)N_NODES * 4);
  int*   rank      = (int*)  alloc((size_t)N_EDGES * 4);
  int*   sortedSrc = (int*)  alloc((size_t)N_EDGES * 4);
  u16*   Wp        = (u16*)  alloc((size_t)HID * FIN * 2);

  hipMemsetAsync(cnt, 0, (size_t)N_NODES * 4, stream);
  // launch graph (5 launches): preph{hist ∥ prepw} -> scan -> gemsc{gemm ∥
  // scatter} -> fused.  scatter needs only rowptr/rank; gemm needs only Wp --
  // independent, so they share one grid and overlap.
  k_preph<<<HIST_BLOCKS + 256, 256, 0, stream>>>(W, Wp, tgt, cnt, rank);
  k_scan<<<1, 1024, 0, stream>>>(cnt, rowptr);
  k_gemsc<<<GEMM_BLOCKS + (N_EDGES + 511) / 512, 512, 0, stream>>>(
      X, Wp, bw, A, Hb, si, sj, tgt, src, rowptr, rank, sortedSrc);
  k_fused<<<(N_NODES + 3) / 4, 256, 0, stream>>>(Hb, si, sj, ba, gamma, beta,
                                                 Wout, bout, rowptr, cnt,
                                                 sortedSrc, out);
}

// Round 9
// 482.808 us; speedup vs baseline: 1.2191x; 1.0039x over previous
//
#include <hip/hip_runtime.h>
#include <hip/hip_bf16.h>
#include <hip/hip_fp16.h>

#define N_NODES 50000
#define N_EDGES 1600000
#define HEADS 8
#define HD 32
#define FIN 256
#define HID 256

typedef unsigned short u16;
typedef unsigned int u32;

typedef short s8v __attribute__((ext_vector_type(8)));   // 8 bf16 (4 VGPRs)
typedef float f4v __attribute__((ext_vector_type(4)));   // 4 fp32 acc
typedef float fx4 __attribute__((ext_vector_type(4)));   // clang vec (NT-able)

// pack 2 fp32 -> 2 bf16 (RNE) in one u32; lowers to v_cvt_pk_bf16_f32 on gfx950
__device__ __forceinline__ u32 pk2(float lo, float hi) {
  __hip_bfloat162 b = __float22bfloat162_rn(make_float2(lo, hi));
  union { __hip_bfloat162 b2; u32 u; } c;
  c.b2 = b;
  return c.u;
}

// ---------------- one-time W pre-pack: Wp[col*256+k] = bf16(W[h][k][d]) -----
__global__ __launch_bounds__(256) void k_prepw(const float* __restrict__ W,
                                               u16* __restrict__ Wp) {
  int id = blockIdx.x * 256 + threadIdx.x;   // grid 256 -> 65536 ids
  int col = id >> 8;
  int k = id & 255;
  int h = col >> 5, d = col & 31;
  Wp[col * 256 + k] = (u16)(pk2(W[h * 8192 + k * 32 + d], 0.f) & 0xFFFFu);
}

// ---------------- combo: MFMA GEMM (391 blocks) ∥ edge histogram (3125) -----
// R9: hist moves off the serial path -- it shares a grid with gemm. They use
// disjoint resources (MFMA/LDS/X-stream vs L2-atomics/int-streams), the best
// remaining overlap candidate after R8 showed scatter∥gemm is ~additive.
#define GEMM_BLOCKS ((N_NODES + 127) / 128)
__global__ __launch_bounds__(512) void k_gemhist(
    const float* __restrict__ X, const u16* __restrict__ Wp,
    const float* __restrict__ bw, const float* __restrict__ A,
    __half* __restrict__ Hb, float* __restrict__ si, float* __restrict__ sj,
    const int* __restrict__ tgt, int* __restrict__ cnt, int* __restrict__ rank) {
  __shared__ __align__(16) u16 Xs[128 * 40];  // [row][k] stride 40
  __shared__ __align__(16) u16 Wt[256 * 40];  // [col][k] stride 40

  if (blockIdx.x >= GEMM_BLOCKS) {
    // ---------------- hist branch ----------------
    int e = (blockIdx.x - GEMM_BLOCKS) * 512 + threadIdx.x;
    if (e < N_EDGES) {
      int tg = __builtin_nontemporal_load(tgt + e);
      rank[e] = atomicAdd(&cnt[tg], 1);
    }
    return;
  }

  // ---------------- gemm branch (R4-winning 128x256 geometry) ----------------
  const int t = threadIdx.x;
  const int m0 = blockIdx.x * 128;
  const int w = t >> 6;
  const int lane = t & 63;
  const int l15 = lane & 15;
  const int quad = lane >> 4;
  const int wm = (w >> 2) * 64;   // wave row offset in block tile
  const int wn = (w & 3) * 64;    // wave col offset in block tile

  f4v acc[4][4];
#pragma unroll
  for (int i = 0; i < 4; i++)
#pragma unroll
    for (int j = 0; j < 4; j++) acc[i][j] = (f4v){0.f, 0.f, 0.f, 0.f};

  const int wcol = t >> 2;        // 0..127 (W staging)
  const int wpart = t & 3;        // 16B part of a 32-k row

  for (int k0 = 0; k0 < FIN; k0 += 32) {
    // stage X tile: 128 rows x 32 k (fp32 -> bf16), read once globally -> NT
#pragma unroll
    for (int p = 0; p < 2; p++) {
      int row = p * 64 + (t >> 3);
      int f4 = t & 7;
      int node = m0 + row;
      fx4 xv = (fx4){0.f, 0.f, 0.f, 0.f};
      if (node < N_NODES)
        xv = __builtin_nontemporal_load((const fx4*)&X[node * FIN + k0 + f4 * 4]);
      u32* dst = (u32*)&Xs[row * 40 + f4 * 4];
      dst[0] = pk2(xv[0], xv[1]);
      dst[1] = pk2(xv[2], xv[3]);
    }
    // stage W tile from pre-packed Wp: 2x coalesced 16B copies per thread
#pragma unroll
    for (int c2 = 0; c2 < 2; c2++) {
      int cc = wcol + c2 * 128;
      *(fx4*)&Wt[cc * 40 + wpart * 8] =
          *(const fx4*)&Wp[cc * 256 + k0 + wpart * 8];
    }
    __syncthreads();
    s8v af[4], bf[4];
#pragma unroll
    for (int mi = 0; mi < 4; mi++)
      af[mi] = *(const s8v*)&Xs[(wm + mi * 16 + l15) * 40 + quad * 8];
#pragma unroll
    for (int ni = 0; ni < 4; ni++)
      bf[ni] = *(const s8v*)&Wt[(wn + ni * 16 + l15) * 40 + quad * 8];
#pragma unroll
    for (int mi = 0; mi < 4; mi++)
#pragma unroll
      for (int ni = 0; ni < 4; ni++)
        acc[mi][ni] = __builtin_amdgcn_mfma_f32_16x16x32_bf16(af[mi], bf[ni], acc[mi][ni], 0, 0, 0);
    __syncthreads();
  }

  // epilogue: bias, store f16 H, fused si/sj
  const int head0 = wn >> 5;
  const int head1 = head0 + 1;
  float c1a0 = A[head0 * 64 + l15],      c1a1 = A[head0 * 64 + 16 + l15];
  float c2a0 = A[head0 * 64 + 32 + l15], c2a1 = A[head0 * 64 + 48 + l15];
  float c1b0 = A[head1 * 64 + l15],      c1b1 = A[head1 * 64 + 16 + l15];
  float c2b0 = A[head1 * 64 + 32 + l15], c2b1 = A[head1 * 64 + 48 + l15];

#pragma unroll
  for (int mi = 0; mi < 4; mi++) {
#pragma unroll
    for (int ni = 0; ni < 4; ni++) {
      float b = bw[wn + ni * 16 + l15];
#pragma unroll
      for (int r = 0; r < 4; r++) acc[mi][ni][r] += b;
    }
    const int rbase = m0 + wm + mi * 16 + quad * 4;
#pragma unroll
    for (int r = 0; r < 4; r++) {
      int node = rbase + r;
      if (node < N_NODES) {
#pragma unroll
        for (int ni = 0; ni < 4; ni++) {
          int col = wn + ni * 16 + l15;
          Hb[node * HID + col] = __float2half_rn(acc[mi][ni][r]);
        }
      }
    }
    float s1a[4], s2a[4], s1b[4], s2b[4];
#pragma unroll
    for (int r = 0; r < 4; r++) {
      s1a[r] = acc[mi][0][r] * c1a0 + acc[mi][1][r] * c1a1;
      s2a[r] = acc[mi][0][r] * c2a0 + acc[mi][1][r] * c2a1;
      s1b[r] = acc[mi][2][r] * c1b0 + acc[mi][3][r] * c1b1;
      s2b[r] = acc[mi][2][r] * c2b0 + acc[mi][3][r] * c2b1;
    }
#pragma unroll
    for (int off = 1; off <= 8; off <<= 1) {
#pragma unroll
      for (int r = 0; r < 4; r++) {
        s1a[r] += __shfl_xor(s1a[r], off);
        s2a[r] += __shfl_xor(s2a[r], off);
        s1b[r] += __shfl_xor(s1b[r], off);
        s2b[r] += __shfl_xor(s2b[r], off);
      }
    }
    if (l15 == 0) {
#pragma unroll
      for (int r = 0; r < 4; r++) {
        int node = rbase + r;
        if (node < N_NODES) {
          si[node * HEADS + head0] = s1a[r];
          sj[node * HEADS + head0] = s2a[r];
          si[node * HEADS + head1] = s1b[r];
          sj[node * HEADS + head1] = s2b[r];
        }
      }
    }
  }
}

// single-block exclusive scan of cnt -> rowptr
#define SCHUNK 49   // 1024 * 49 = 50176 >= N_NODES
__global__ __launch_bounds__(1024) void k_scan(const int* __restrict__ cnt,
                                               int* __restrict__ rowptr) {
  __shared__ int s[1024];
  const int t = threadIdx.x;
  const int base = t * SCHUNK;
  int sum = 0;
#pragma unroll 7
  for (int j = 0; j < SCHUNK; j++) {
    int i = base + j;
    sum += (i < N_NODES) ? cnt[i] : 0;
  }
  s[t] = sum;
  __syncthreads();
  int x = sum;
  for (int off = 1; off < 1024; off <<= 1) {
    int y = (t >= off) ? s[t - off] : 0;
    __syncthreads();
    x += y;
    s[t] = x;
    __syncthreads();
  }
  int run = x - sum;   // exclusive prefix of this thread's chunk
#pragma unroll 7
  for (int j = 0; j < SCHUNK; j++) {
    int i = base + j;
    if (i < N_NODES) {
      rowptr[i] = run;
      run += cnt[i];
    }
  }
}

// pure permutation store -- zero atomics (contention paid once in hist)
__global__ void k_scatter(const int* __restrict__ tgt, const int* __restrict__ src,
                          const int* __restrict__ rowptr, const int* __restrict__ rank,
                          int* __restrict__ sortedSrc) {
  int e = blockIdx.x * 256 + threadIdx.x;
  if (e < N_EDGES) {
    int tg = __builtin_nontemporal_load(tgt + e);
    int sc = __builtin_nontemporal_load(src + e);
    int rk = __builtin_nontemporal_load(rank + e);
    sortedSrc[rowptr[tg] + rk] = sc;
  }
}

// ---------------- fused: softmax-agg + skip + ELU + LN + head-mean + Wout + ELU
// Wave-per-node, zero LDS/barriers. R9: unroll 8 in the gather loop -> ~8
// concurrent dependent-load chains per wave (was 4) to attack the 55% stall.
__global__ __launch_bounds__(256) void k_fused(
    const __half* __restrict__ Hb, const float* __restrict__ si,
    const float* __restrict__ sj, const float* __restrict__ ba,
    const float* __restrict__ gamma, const float* __restrict__ beta,
    const float* __restrict__ Wout, const float* __restrict__ bout,
    const int* __restrict__ rowptr, const int* __restrict__ cnt,
    const int* __restrict__ sortedSrc, float* __restrict__ out) {
  const int t = threadIdx.x;
  const int lane = t & 63;
  const int n = blockIdx.x * 4 + (t >> 6);   // grid = 12500, 4 nodes/block exact
  const int cg = lane & 31;                  // col group: cols cg*8 .. cg*8+7
  const int es = lane >> 5;                  // edge-slot stride lane 0/1
  const int hh = cg >> 2;                    // head of this col group
  const int start = rowptr[n];
  const int deg = cnt[n];

  const float sb = si[n * HEADS + hh] + ba[hh];
  const char* hbBase = (const char*)Hb + 16 * cg;
  const int* ss = sortedSrc + start;

  float acc[8] = {0.f, 0.f, 0.f, 0.f, 0.f, 0.f, 0.f, 0.f};
  float den = 0.f;
#pragma unroll 8
  for (int slot = es; slot < deg; slot += 2) {
    int s = __builtin_nontemporal_load(ss + slot);  // streamed, read-once
    float e = sb + sj[s * HEADS + hh];
    e = (e >= 0.f) ? e : 0.2f * e;
    float exv = __expf(e);
    float4 hb4 = *(const float4*)(hbBase + (size_t)s * (HID * 2));
    const __half2* hp = (const __half2*)&hb4;
#pragma unroll
    for (int d = 0; d < 4; d++) {
      acc[2 * d]     += exv * __low2float(hp[d]);   // v_fma_mix_f32
      acc[2 * d + 1] += exv * __high2float(hp[d]);
    }
    den += exv;
  }
#pragma unroll
  for (int j = 0; j < 8; j++) acc[j] += __shfl_xor(acc[j], 32);
  den += __shfl_xor(den, 32);

  // skip connection + ELU for this lane's 8 cols
  float4 h4 = *(const float4*)((const char*)Hb + (size_t)n * (HID * 2) + 16 * cg);
  const __half2* hq = (const __half2*)&h4;
  float inv = (deg > 0) ? __fdividef(1.f, den) : 0.f;
  float v[8], sum = 0.f, sq = 0.f;
#pragma unroll
  for (int j = 0; j < 8; j++) {
    float hv = (j & 1) ? __high2float(hq[j >> 1]) : __low2float(hq[j >> 1]);
    float x = acc[j] * inv + hv;
    x = (x > 0.f) ? x : (__expf(x) - 1.f);
    v[j] = x;
    sum += x;
    sq += x * x;
  }
  // LayerNorm over the head's 32 cols: in-lane 8 + 4-lane group (xor 1,2)
  sum += __shfl_xor(sum, 1); sq += __shfl_xor(sq, 1);
  sum += __shfl_xor(sum, 2); sq += __shfl_xor(sq, 2);
  float mu = sum * (1.f / 32.f);
  float var = sq * (1.f / 32.f) - mu * mu;
  float rstd = rsqrtf(var + 1e-5f);
  fx4 g0 = *(const fx4*)&gamma[cg * 8];
  fx4 g1 = *(const fx4*)&gamma[cg * 8 + 4];
  fx4 b0 = *(const fx4*)&beta[cg * 8];
  fx4 b1 = *(const fx4*)&beta[cg * 8 + 4];
  float m2[8];
#pragma unroll
  for (int j = 0; j < 8; j++) {
    float g = (j < 4) ? g0[j] : g1[j - 4];
    float bb = (j < 4) ? b0[j] : b1[j - 4];
    m2[j] = (v[j] - mu) * rstd * g + bb;
  }
  // head-mean: sum over heads = lanes differing in cg bits 2..4
#pragma unroll
  for (int j = 0; j < 8; j++) {
    m2[j] += __shfl_xor(m2[j], 4);
    m2[j] += __shfl_xor(m2[j], 8);
    m2[j] += __shfl_xor(m2[j], 16);
  }
  // Output projection: lane owns cols 4*lane..4*lane+3 (coalesced Wout rows)
  fx4 y = *(const fx4*)&bout[4 * lane];
#pragma unroll
  for (int q = 0; q < 4; q++) {
    float mv[8];
#pragma unroll
    for (int j = 0; j < 8; j++) mv[j] = __shfl(m2[j], q) * 0.125f;
#pragma unroll
    for (int j = 0; j < 8; j++) {
      fx4 w4 = *(const fx4*)&Wout[(q * 8 + j) * HID + 4 * lane];
      y += mv[j] * w4;
    }
  }
#pragma unroll
  for (int c = 0; c < 4; c++) y[c] = (y[c] > 0.f) ? y[c] : (__expf(y[c]) - 1.f);
  __builtin_nontemporal_store(y, (fx4*)&out[(size_t)n * HID + 4 * lane]);
}

extern "C" void kernel_launch(void* const* d_in, const int* in_sizes, int n_in,
                              void* d_out, int out_size, void* d_ws, size_t ws_size,
                              hipStream_t stream) {
  const float* X     = (const float*)d_in[0];
  const int*   EI    = (const int*)d_in[1];
  const float* W     = (const float*)d_in[2];
  const float* bw    = (const float*)d_in[3];
  const float* A     = (const float*)d_in[4];
  const float* ba    = (const float*)d_in[5];
  const float* gamma = (const float*)d_in[6];
  const float* beta  = (const float*)d_in[7];
  const float* Wout  = (const float*)d_in[8];
  const float* bout  = (const float*)d_in[9];
  float* out = (float*)d_out;
  const int* tgt = EI;
  const int* src = EI + N_EDGES;

  char* ws = (char*)d_ws;
  size_t off = 0;
  auto alloc = [&](size_t bytes) -> void* {
    void* p = ws + off;
    off += bytes;
    off = (off + 255) & ~(size_t)255;
    return p;
  };
  __half* Hb       = (__half*)alloc((size_t)N_NODES * HID * 2);
  float* si        = (float*)alloc((size_t)N_NODES * HEADS * 4);
  float* sj        = (float*)alloc((size_t)N_NODES * HEADS * 4);
  int*   cnt       = (int*)  alloc((size_t)N_NODES * 4);
  int*   rowptr    = (int*)  alloc((size_t)N_NODES * 4);
  int*   rank      = (int*)  alloc((size_t)N_EDGES * 4);
  int*   sortedSrc = (int*)  alloc((size_t)N_EDGES * 4);
  u16*   Wp        = (u16*)  alloc((size_t)HID * FIN * 2);

  hipMemsetAsync(cnt, 0, (size_t)N_NODES * 4, stream);
  // launch graph: prepw (tiny) -> {gemm ∥ hist} -> scan -> scatter -> fused.
  // hist leaves the serial path; scan/scatter need its cnt/rank output.
  k_prepw<<<256, 256, 0, stream>>>(W, Wp);
  k_gemhist<<<GEMM_BLOCKS + (N_EDGES + 511) / 512, 512, 0, stream>>>(
      X, Wp, bw, A, Hb, si, sj, tgt, cnt, rank);
  k_scan<<<1, 1024, 0, stream>>>(cnt, rowptr);
  k_scatter<<<(N_EDGES + 255) / 256, 256, 0, stream>>>(tgt, src, rowptr, rank, sortedSrc);
  k_fused<<<(N_NODES + 3) / 4, 256, 0, stream>>>(Hb, si, sj, ba, gamma, beta,
                                                 Wout, bout, rowptr, cnt,
                                                 sortedSrc, out);
}

// Round 10
// 470.739 us; speedup vs baseline: 1.2504x; 1.0256x over previous
//
#include <hip/hip_runtime.h>
#include <hip/hip_bf16.h>
#include <hip/hip_fp16.h>

#define N_NODES 50000
#define N_EDGES 1600000
#define HEADS 8
#define HD 32
#define FIN 256
#define HID 256

typedef unsigned short u16;
typedef unsigned int u32;

typedef short s8v __attribute__((ext_vector_type(8)));   // 8 bf16 (4 VGPRs)
typedef float f4v __attribute__((ext_vector_type(4)));   // 4 fp32 acc
typedef float fx4 __attribute__((ext_vector_type(4)));   // clang vec (NT-able)

// pack 2 fp32 -> 2 bf16 (RNE) in one u32; lowers to v_cvt_pk_bf16_f32 on gfx950
__device__ __forceinline__ u32 pk2(float lo, float hi) {
  __hip_bfloat162 b = __float22bfloat162_rn(make_float2(lo, hi));
  union { __hip_bfloat162 b2; u32 u; } c;
  c.b2 = b;
  return c.u;
}

// ---------------- one-time W pre-pack: Wp[col*256+k] = bf16(W[h][k][d]) -----
__global__ __launch_bounds__(256) void k_prepw(const float* __restrict__ W,
                                               u16* __restrict__ Wp) {
  int id = blockIdx.x * 256 + threadIdx.x;   // grid 256 -> 65536 ids
  int col = id >> 8;
  int k = id & 255;
  int h = col >> 5, d = col & 31;
  Wp[col * 256 + k] = (u16)(pk2(W[h * 8192 + k * 32 + d], 0.f) & 0xFFFFu);
}

// ---------------- combo: MFMA GEMM (391 blocks) ∥ edge histogram (3125) -----
// Proven in R9: hist off the serial path bought ~15 us (disjoint resources).
#define GEMM_BLOCKS ((N_NODES + 127) / 128)
__global__ __launch_bounds__(512) void k_gemhist(
    const float* __restrict__ X, const u16* __restrict__ Wp,
    const float* __restrict__ bw, const float* __restrict__ A,
    __half* __restrict__ Hb, float* __restrict__ si, float* __restrict__ sj,
    const int* __restrict__ tgt, int* __restrict__ cnt, int* __restrict__ rank) {
  __shared__ __align__(16) u16 Xs[128 * 40];  // [row][k] stride 40
  __shared__ __align__(16) u16 Wt[256 * 40];  // [col][k] stride 40

  if (blockIdx.x >= GEMM_BLOCKS) {
    // ---------------- hist branch ----------------
    int e = (blockIdx.x - GEMM_BLOCKS) * 512 + threadIdx.x;
    if (e < N_EDGES) {
      int tg = __builtin_nontemporal_load(tgt + e);
      rank[e] = atomicAdd(&cnt[tg], 1);
    }
    return;
  }

  // ---------------- gemm branch (R4-winning 128x256 geometry) ----------------
  const int t = threadIdx.x;
  const int m0 = blockIdx.x * 128;
  const int w = t >> 6;
  const int lane = t & 63;
  const int l15 = lane & 15;
  const int quad = lane >> 4;
  const int wm = (w >> 2) * 64;   // wave row offset in block tile
  const int wn = (w & 3) * 64;    // wave col offset in block tile

  f4v acc[4][4];
#pragma unroll
  for (int i = 0; i < 4; i++)
#pragma unroll
    for (int j = 0; j < 4; j++) acc[i][j] = (f4v){0.f, 0.f, 0.f, 0.f};

  const int wcol = t >> 2;        // 0..127 (W staging)
  const int wpart = t & 3;        // 16B part of a 32-k row

  for (int k0 = 0; k0 < FIN; k0 += 32) {
    // stage X tile: 128 rows x 32 k (fp32 -> bf16), read once globally -> NT
#pragma unroll
    for (int p = 0; p < 2; p++) {
      int row = p * 64 + (t >> 3);
      int f4 = t & 7;
      int node = m0 + row;
      fx4 xv = (fx4){0.f, 0.f, 0.f, 0.f};
      if (node < N_NODES)
        xv = __builtin_nontemporal_load((const fx4*)&X[node * FIN + k0 + f4 * 4]);
      u32* dst = (u32*)&Xs[row * 40 + f4 * 4];
      dst[0] = pk2(xv[0], xv[1]);
      dst[1] = pk2(xv[2], xv[3]);
    }
    // stage W tile from pre-packed Wp: 2x coalesced 16B copies per thread
#pragma unroll
    for (int c2 = 0; c2 < 2; c2++) {
      int cc = wcol + c2 * 128;
      *(fx4*)&Wt[cc * 40 + wpart * 8] =
          *(const fx4*)&Wp[cc * 256 + k0 + wpart * 8];
    }
    __syncthreads();
    s8v af[4], bf[4];
#pragma unroll
    for (int mi = 0; mi < 4; mi++)
      af[mi] = *(const s8v*)&Xs[(wm + mi * 16 + l15) * 40 + quad * 8];
#pragma unroll
    for (int ni = 0; ni < 4; ni++)
      bf[ni] = *(const s8v*)&Wt[(wn + ni * 16 + l15) * 40 + quad * 8];
#pragma unroll
    for (int mi = 0; mi < 4; mi++)
#pragma unroll
      for (int ni = 0; ni < 4; ni++)
        acc[mi][ni] = __builtin_amdgcn_mfma_f32_16x16x32_bf16(af[mi], bf[ni], acc[mi][ni], 0, 0, 0);
    __syncthreads();
  }

  // epilogue: bias, store f16 H, fused si/sj
  const int head0 = wn >> 5;
  const int head1 = head0 + 1;
  float c1a0 = A[head0 * 64 + l15],      c1a1 = A[head0 * 64 + 16 + l15];
  float c2a0 = A[head0 * 64 + 32 + l15], c2a1 = A[head0 * 64 + 48 + l15];
  float c1b0 = A[head1 * 64 + l15],      c1b1 = A[head1 * 64 + 16 + l15];
  float c2b0 = A[head1 * 64 + 32 + l15], c2b1 = A[head1 * 64 + 48 + l15];

#pragma unroll
  for (int mi = 0; mi < 4; mi++) {
#pragma unroll
    for (int ni = 0; ni < 4; ni++) {
      float b = bw[wn + ni * 16 + l15];
#pragma unroll
      for (int r = 0; r < 4; r++) acc[mi][ni][r] += b;
    }
    const int rbase = m0 + wm + mi * 16 + quad * 4;
#pragma unroll
    for (int r = 0; r < 4; r++) {
      int node = rbase + r;
      if (node < N_NODES) {
#pragma unroll
        for (int ni = 0; ni < 4; ni++) {
          int col = wn + ni * 16 + l15;
          Hb[node * HID + col] = __float2half_rn(acc[mi][ni][r]);
        }
      }
    }
    float s1a[4], s2a[4], s1b[4], s2b[4];
#pragma unroll
    for (int r = 0; r < 4; r++) {
      s1a[r] = acc[mi][0][r] * c1a0 + acc[mi][1][r] * c1a1;
      s2a[r] = acc[mi][0][r] * c2a0 + acc[mi][1][r] * c2a1;
      s1b[r] = acc[mi][2][r] * c1b0 + acc[mi][3][r] * c1b1;
      s2b[r] = acc[mi][2][r] * c2b0 + acc[mi][3][r] * c2b1;
    }
#pragma unroll
    for (int off = 1; off <= 8; off <<= 1) {
#pragma unroll
      for (int r = 0; r < 4; r++) {
        s1a[r] += __shfl_xor(s1a[r], off);
        s2a[r] += __shfl_xor(s2a[r], off);
        s1b[r] += __shfl_xor(s1b[r], off);
        s2b[r] += __shfl_xor(s2b[r], off);
      }
    }
    if (l15 == 0) {
#pragma unroll
      for (int r = 0; r < 4; r++) {
        int node = rbase + r;
        if (node < N_NODES) {
          si[node * HEADS + head0] = s1a[r];
          sj[node * HEADS + head0] = s2a[r];
          si[node * HEADS + head1] = s1b[r];
          sj[node * HEADS + head1] = s2b[r];
        }
      }
    }
  }
}

// single-block exclusive scan of cnt -> rowptr
#define SCHUNK 49   // 1024 * 49 = 50176 >= N_NODES
__global__ __launch_bounds__(1024) void k_scan(const int* __restrict__ cnt,
                                               int* __restrict__ rowptr) {
  __shared__ int s[1024];
  const int t = threadIdx.x;
  const int base = t * SCHUNK;
  int sum = 0;
#pragma unroll 7
  for (int j = 0; j < SCHUNK; j++) {
    int i = base + j;
    sum += (i < N_NODES) ? cnt[i] : 0;
  }
  s[t] = sum;
  __syncthreads();
  int x = sum;
  for (int off = 1; off < 1024; off <<= 1) {
    int y = (t >= off) ? s[t - off] : 0;
    __syncthreads();
    x += y;
    s[t] = x;
    __syncthreads();
  }
  int run = x - sum;   // exclusive prefix of this thread's chunk
#pragma unroll 7
  for (int j = 0; j < SCHUNK; j++) {
    int i = base + j;
    if (i < N_NODES) {
      rowptr[i] = run;
      run += cnt[i];
    }
  }
}

// pure permutation store -- zero atomics (contention paid once in hist)
__global__ void k_scatter(const int* __restrict__ tgt, const int* __restrict__ src,
                          const int* __restrict__ rowptr, const int* __restrict__ rank,
                          int* __restrict__ sortedSrc) {
  int e = blockIdx.x * 256 + threadIdx.x;
  if (e < N_EDGES) {
    int tg = __builtin_nontemporal_load(tgt + e);
    int sc = __builtin_nontemporal_load(src + e);
    int rk = __builtin_nontemporal_load(rank + e);
    sortedSrc[rowptr[tg] + rk] = sc;
  }
}

// ---------------- fused: softmax-agg + skip + ELU + LN + head-mean + Wout + ELU
// Wave-per-node, zero LDS/barriers. unroll 4 (PROVEN: R9's unroll 8 pushed
// VGPR 36->60, occupancy 61->35%, +13 us -- TLP beats deeper ILP here).
__global__ __launch_bounds__(256) void k_fused(
    const __half* __restrict__ Hb, const float* __restrict__ si,
    const float* __restrict__ sj, const float* __restrict__ ba,
    const float* __restrict__ gamma, const float* __restrict__ beta,
    const float* __restrict__ Wout, const float* __restrict__ bout,
    const int* __restrict__ rowptr, const int* __restrict__ cnt,
    const int* __restrict__ sortedSrc, float* __restrict__ out) {
  const int t = threadIdx.x;
  const int lane = t & 63;
  const int n = blockIdx.x * 4 + (t >> 6);   // grid = 12500, 4 nodes/block exact
  const int cg = lane & 31;                  // col group: cols cg*8 .. cg*8+7
  const int es = lane >> 5;                  // edge-slot stride lane 0/1
  const int hh = cg >> 2;                    // head of this col group
  const int start = rowptr[n];
  const int deg = cnt[n];

  const float sb = si[n * HEADS + hh] + ba[hh];
  const char* hbBase = (const char*)Hb + 16 * cg;
  const int* ss = sortedSrc + start;

  float acc[8] = {0.f, 0.f, 0.f, 0.f, 0.f, 0.f, 0.f, 0.f};
  float den = 0.f;
#pragma unroll 4
  for (int slot = es; slot < deg; slot += 2) {
    int s = __builtin_nontemporal_load(ss + slot);  // streamed, read-once
    float e = sb + sj[s * HEADS + hh];
    e = (e >= 0.f) ? e : 0.2f * e;
    float exv = __expf(e);
    float4 hb4 = *(const float4*)(hbBase + (size_t)s * (HID * 2));
    const __half2* hp = (const __half2*)&hb4;
#pragma unroll
    for (int d = 0; d < 4; d++) {
      acc[2 * d]     += exv * __low2float(hp[d]);   // v_fma_mix_f32
      acc[2 * d + 1] += exv * __high2float(hp[d]);
    }
    den += exv;
  }
#pragma unroll
  for (int j = 0; j < 8; j++) acc[j] += __shfl_xor(acc[j], 32);
  den += __shfl_xor(den, 32);

  // skip connection + ELU for this lane's 8 cols
  float4 h4 = *(const float4*)((const char*)Hb + (size_t)n * (HID * 2) + 16 * cg);
  const __half2* hq = (const __half2*)&h4;
  float inv = (deg > 0) ? __fdividef(1.f, den) : 0.f;
  float v[8], sum = 0.f, sq = 0.f;
#pragma unroll
  for (int j = 0; j < 8; j++) {
    float hv = (j & 1) ? __high2float(hq[j >> 1]) : __low2float(hq[j >> 1]);
    float x = acc[j] * inv + hv;
    x = (x > 0.f) ? x : (__expf(x) - 1.f);
    v[j] = x;
    sum += x;
    sq += x * x;
  }
  // LayerNorm over the head's 32 cols: in-lane 8 + 4-lane group (xor 1,2)
  sum += __shfl_xor(sum, 1); sq += __shfl_xor(sq, 1);
  sum += __shfl_xor(sum, 2); sq += __shfl_xor(sq, 2);
  float mu = sum * (1.f / 32.f);
  float var = sq * (1.f / 32.f) - mu * mu;
  float rstd = rsqrtf(var + 1e-5f);
  fx4 g0 = *(const fx4*)&gamma[cg * 8];
  fx4 g1 = *(const fx4*)&gamma[cg * 8 + 4];
  fx4 b0 = *(const fx4*)&beta[cg * 8];
  fx4 b1 = *(const fx4*)&beta[cg * 8 + 4];
  float m2[8];
#pragma unroll
  for (int j = 0; j < 8; j++) {
    float g = (j < 4) ? g0[j] : g1[j - 4];
    float bb = (j < 4) ? b0[j] : b1[j - 4];
    m2[j] = (v[j] - mu) * rstd * g + bb;
  }
  // head-mean: sum over heads = lanes differing in cg bits 2..4
#pragma unroll
  for (int j = 0; j < 8; j++) {
    m2[j] += __shfl_xor(m2[j], 4);
    m2[j] += __shfl_xor(m2[j], 8);
    m2[j] += __shfl_xor(m2[j], 16);
  }
  // Output projection: lane owns cols 4*lane..4*lane+3 (coalesced Wout rows)
  fx4 y = *(const fx4*)&bout[4 * lane];
#pragma unroll
  for (int q = 0; q < 4; q++) {
    float mv[8];
#pragma unroll
    for (int j = 0; j < 8; j++) mv[j] = __shfl(m2[j], q) * 0.125f;
#pragma unroll
    for (int j = 0; j < 8; j++) {
      fx4 w4 = *(const fx4*)&Wout[(q * 8 + j) * HID + 4 * lane];
      y += mv[j] * w4;
    }
  }
#pragma unroll
  for (int c = 0; c < 4; c++) y[c] = (y[c] > 0.f) ? y[c] : (__expf(y[c]) - 1.f);
  __builtin_nontemporal_store(y, (fx4*)&out[(size_t)n * HID + 4 * lane]);
}

extern "C" void kernel_launch(void* const* d_in, const int* in_sizes, int n_in,
                              void* d_out, int out_size, void* d_ws, size_t ws_size,
                              hipStream_t stream) {
  const float* X     = (const float*)d_in[0];
  const int*   EI    = (const int*)d_in[1];
  const float* W     = (const float*)d_in[2];
  const float* bw    = (const float*)d_in[3];
  const float* A     = (const float*)d_in[4];
  const float* ba    = (const float*)d_in[5];
  const float* gamma = (const float*)d_in[6];
  const float* beta  = (const float*)d_in[7];
  const float* Wout  = (const float*)d_in[8];
  const float* bout  = (const float*)d_in[9];
  float* out = (float*)d_out;
  const int* tgt = EI;
  const int* src = EI + N_EDGES;

  char* ws = (char*)d_ws;
  size_t off = 0;
  auto alloc = [&](size_t bytes) -> void* {
    void* p = ws + off;
    off += bytes;
    off = (off + 255) & ~(size_t)255;
    return p;
  };
  __half* Hb       = (__half*)alloc((size_t)N_NODES * HID * 2);
  float* si        = (float*)alloc((size_t)N_NODES * HEADS * 4);
  float* sj        = (float*)alloc((size_t)N_NODES * HEADS * 4);
  int*   cnt       = (int*)  alloc((size_t)N_NODES * 4);
  int*   rowptr    = (int*)  alloc((size_t)N_NODES * 4);
  int*   rank      = (int*)  alloc((size_t)N_EDGES * 4);
  int*   sortedSrc = (int*)  alloc((size_t)N_EDGES * 4);
  u16*   Wp        = (u16*)  alloc((size_t)HID * FIN * 2);

  hipMemsetAsync(cnt, 0, (size_t)N_NODES * 4, stream);
  // launch graph: prepw (tiny) -> {gemm ∥ hist} -> scan -> scatter -> fused.
  k_prepw<<<256, 256, 0, stream>>>(W, Wp);
  k_gemhist<<<GEMM_BLOCKS + (N_EDGES + 511) / 512, 512, 0, stream>>>(
      X, Wp, bw, A, Hb, si, sj, tgt, cnt, rank);
  k_scan<<<1, 1024, 0, stream>>>(cnt, rowptr);
  k_scatter<<<(N_EDGES + 255) / 256, 256, 0, stream>>>(tgt, src, rowptr, rank, sortedSrc);
  k_fused<<<(N_NODES + 3) / 4, 256, 0, stream>>>(Hb, si, sj, ba, gamma, beta,
                                                 Wout, bout, rowptr, cnt,
                                                 sortedSrc, out);
}